// Round 2
// baseline (2856.027 us; speedup 1.0000x reference)
//
#include <hip/hip_runtime.h>
#include <hip/hip_bf16.h>
#include <stdint.h>

// ---------------------------------------------------------------------------
// Network_60163901882451: conv(3->32->64->128, 3x3 SAME, BN train-mode, relu)
// on 8192 9x9 images -> FC 10368->128 -> 2x graph filters (K=3) -> 5-way head.
// Round 1: fix workspace overflow (peak live cut to ~243 MiB via aliasing).
// Activations bf16 [img][px][oc]; BN+relu fused into next consumer's load.
// ---------------------------------------------------------------------------

#define NIMG 8192
#define NPIX 81
#define FLAT 10368

typedef __hip_bfloat16 bf16;

__device__ __forceinline__ float bflo(unsigned u) { return __uint_as_float(u << 16); }
__device__ __forceinline__ float bfhi(unsigned u) { return __uint_as_float(u & 0xffff0000u); }

__global__ void fill_sentinel(float* __restrict__ out, int n) {
    int i = blockIdx.x * 256 + threadIdx.x;
    if (i < n) out[i] = 1.0e9f;   // ws_size-too-small signature
}

// ---------------- weight pre-transposes ------------------------------------
__global__ void prep_conv_w(const float* __restrict__ c1w, const float* __restrict__ c2w,
                            const float* __restrict__ c3w,
                            float* __restrict__ w1t, float* __restrict__ w2t,
                            float* __restrict__ w3t) {
    int i0 = blockIdx.x * blockDim.x + threadIdx.x;
    int stride = gridDim.x * blockDim.x;
    // wNt[(ci*9+k)*CO + oc] = cNw[oc][ci][k]
    for (int i = i0; i < 27 * 32; i += stride)   w1t[i] = c1w[(i & 31) * 27 + (i >> 5)];
    for (int i = i0; i < 288 * 64; i += stride)  w2t[i] = c2w[(i & 63) * 288 + (i >> 6)];
    for (int i = i0; i < 576 * 128; i += stride) w3t[i] = c3w[(i & 127) * 576 + (i >> 7)];
}

// ewt[(px*128+oc)*128 + e] = encw[e][oc*81+px]   (runs after conv3; aliases x2)
__global__ void prep_enc_w(const float* __restrict__ encw, float* __restrict__ ewt) {
    int i0 = blockIdx.x * blockDim.x + threadIdx.x;
    int stride = gridDim.x * blockDim.x;
    for (int i = i0; i < FLAT * 128; i += stride) {
        int e = i & 127, kp = i >> 7;
        int px = kp >> 7, oc = kp & 127;
        ewt[i] = encw[(size_t)e * FLAT + oc * 81 + px];
    }
}

// ---------------- direct conv core (9x9, pad 1, LDS rows [11][12]) ---------
__device__ __forceinline__ void load_row(const float* __restrict__ p, float* r) {
    float4 a = *(const float4*)p;
    float4 b = *(const float4*)(p + 4);
    float4 c = *(const float4*)(p + 8);
    r[0]=a.x; r[1]=a.y; r[2]=a.z;  r[3]=a.w;
    r[4]=b.x; r[5]=b.y; r[6]=b.z;  r[7]=b.w;
    r[8]=c.x; r[9]=c.y; r[10]=c.z; r[11]=c.w;
}

__device__ __forceinline__ void conv_body(const float* __restrict__ inp, // LDS [11][12]
                                          const float* __restrict__ wv, float* acc) {
    float rb[3][12];
    load_row(inp, rb[0]);
    load_row(inp + 12, rb[1]);
#pragma unroll
    for (int oy = 0; oy < 9; oy++) {
        load_row(inp + (oy + 2) * 12, rb[(oy + 2) % 3]);
#pragma unroll
        for (int ky = 0; ky < 3; ky++) {
            const float* r = rb[(oy + ky) % 3];
#pragma unroll
            for (int ox = 0; ox < 9; ox++) {
                float s = acc[oy * 9 + ox];
                s = fmaf(r[ox + 0], wv[ky * 3 + 0], s);
                s = fmaf(r[ox + 1], wv[ky * 3 + 1], s);
                s = fmaf(r[ox + 2], wv[ky * 3 + 2], s);
                acc[oy * 9 + ox] = s;
            }
        }
    }
}

// ---------------- conv1: fp32 in [img][3][81], out bf16 [img][81][32] ------
__global__ __launch_bounds__(128) void conv1_kernel(const float* __restrict__ xin,
        const float* __restrict__ wt, const float* __restrict__ bias,
        bf16* __restrict__ xout) {
    __shared__ __align__(16) float lds[4 * 3 * 132];
    int t = threadIdx.x;
    int img0 = blockIdx.x * 4;
    for (int i = t; i < 4 * 3 * 132; i += 128) lds[i] = 0.f;
    __syncthreads();
    const float* src = xin + (size_t)img0 * 243;
    for (int i = t; i < 4 * 243; i += 128) {
        int il = i / 243, rem = i - il * 243;
        int ci = rem / 81, px = rem - ci * 81;
        lds[(il * 3 + ci) * 132 + (px / 9 + 1) * 12 + (px % 9) + 1] = src[i];
    }
    __syncthreads();
    int oc = t & 31, il = t >> 5;
    const float* base = lds + il * 3 * 132;
    float acc[81];
    float bb = bias[oc];
#pragma unroll
    for (int i = 0; i < 81; i++) acc[i] = bb;
#pragma unroll
    for (int ci = 0; ci < 3; ci++) {
        float wv[9];
#pragma unroll
        for (int k = 0; k < 9; k++) wv[k] = wt[(ci * 9 + k) * 32 + oc];
        conv_body(base + ci * 132, wv, acc);
    }
    bf16* dst = xout + (size_t)(img0 + il) * 81 * 32 + oc;
#pragma unroll
    for (int p = 0; p < 81; p++) dst[p * 32] = __float2bfloat16(acc[p]);
}

// ------- conv2/conv3: bf16 in [img][81][CI] (+BN/relu), out [img][81][CO] --
template <int CI, int CO, int IMGS>
__global__ __launch_bounds__(128) void convBN_kernel(const bf16* __restrict__ xin,
        const float* __restrict__ wt, const float* __restrict__ bias,
        const float* __restrict__ stats, bf16* __restrict__ xout) {
    __shared__ __align__(16) float lds[IMGS * CI * 132];
    __shared__ float sst[2 * CI];
    int t = threadIdx.x;
    int img0 = blockIdx.x * IMGS;
    for (int i = t; i < IMGS * CI * 132; i += 128) lds[i] = 0.f;
    for (int i = t; i < 2 * CI; i += 128) sst[i] = stats[i];
    __syncthreads();
    const bf16* src = xin + (size_t)img0 * 81 * CI;
    constexpr int TOT8 = IMGS * 81 * CI / 8;
    for (int i8 = t; i8 < TOT8; i8 += 128) {
        int e0 = i8 * 8;
        int il = e0 / (81 * CI);
        int rem = e0 - il * (81 * CI);
        int px = rem / CI, ci0 = rem - px * CI;
        uint4 u = *(const uint4*)(src + e0);
        float vv[8] = {bflo(u.x), bfhi(u.x), bflo(u.y), bfhi(u.y),
                       bflo(u.z), bfhi(u.z), bflo(u.w), bfhi(u.w)};
        float* dst = lds + il * CI * 132 + ci0 * 132 + (px / 9 + 1) * 12 + (px % 9) + 1;
#pragma unroll
        for (int j = 0; j < 8; j++) {
            float v = fmaxf(fmaf(vv[j], sst[ci0 + j], sst[CI + ci0 + j]), 0.f);
            dst[j * 132] = v;
        }
    }
    __syncthreads();
    int oc = t % CO, il = t / CO;
    const float* base = lds + il * CI * 132;
    float acc[81];
    float bb = bias[oc];
#pragma unroll
    for (int i = 0; i < 81; i++) acc[i] = bb;
    float wnext[9];
#pragma unroll
    for (int k = 0; k < 9; k++) wnext[k] = wt[k * CO + oc];
#pragma unroll 1
    for (int ci = 0; ci < CI; ci++) {
        float wv[9];
#pragma unroll
        for (int k = 0; k < 9; k++) wv[k] = wnext[k];
        if (ci + 1 < CI) {
#pragma unroll
            for (int k = 0; k < 9; k++) wnext[k] = wt[((ci + 1) * 9 + k) * CO + oc];
        }
        conv_body(base + ci * 132, wv, acc);
    }
    bf16* dst = xout + (size_t)(img0 + il) * 81 * CO + oc;
#pragma unroll
    for (int p = 0; p < 81; p++) dst[(size_t)p * CO] = __float2bfloat16(acc[p]);
}

// ---------------- per-channel sum / sumsq over [663552][CO] bf16 -----------
template <int CO>
__global__ __launch_bounds__(256) void stats_pass(const bf16* __restrict__ x,
                                                  float* __restrict__ acc) {
    constexpr int CH8 = CO / 8;     // channel-octets
    constexpr int NG = 256 / CH8;   // row groups per block
    __shared__ float ss[2048], sq2[2048];
    int t = threadIdx.x;
    int cg = t % CH8, grp = t / CH8;
    float s[8], q[8];
#pragma unroll
    for (int j = 0; j < 8; j++) { s[j] = 0.f; q[j] = 0.f; }
    const int ROWS = NIMG * 81;
    for (int row = blockIdx.x * NG + grp; row < ROWS; row += gridDim.x * NG) {
        uint4 u = *(const uint4*)(x + (size_t)row * CO + cg * 8);
        float vv[8] = {bflo(u.x), bfhi(u.x), bflo(u.y), bfhi(u.y),
                       bflo(u.z), bfhi(u.z), bflo(u.w), bfhi(u.w)};
#pragma unroll
        for (int j = 0; j < 8; j++) { s[j] += vv[j]; q[j] = fmaf(vv[j], vv[j], q[j]); }
    }
#pragma unroll
    for (int j = 0; j < 8; j++) {
        ss[grp * CO + cg * 8 + j] = s[j];
        sq2[grp * CO + cg * 8 + j] = q[j];
    }
    __syncthreads();
    for (int step = NG / 2; step > 0; step >>= 1) {
        if (grp < step) {
#pragma unroll
            for (int j = 0; j < 8; j++) {
                ss[grp * CO + cg * 8 + j] += ss[(grp + step) * CO + cg * 8 + j];
                sq2[grp * CO + cg * 8 + j] += sq2[(grp + step) * CO + cg * 8 + j];
            }
        }
        __syncthreads();
    }
    if (grp == 0) {
#pragma unroll
        for (int j = 0; j < 8; j++) {
            atomicAdd(&acc[cg * 8 + j], ss[cg * 8 + j]);
            atomicAdd(&acc[CO + cg * 8 + j], sq2[cg * 8 + j]);
        }
    }
}

// stats -> fused scale/shift:  y = x*scale + shift  (= gamma*(x-m)*istd + beta)
template <int CO>
__global__ void stats_fin(const float* __restrict__ acc, const float* __restrict__ gamma,
                          const float* __restrict__ beta, float* __restrict__ st) {
    int c = threadIdx.x;
    if (c < CO) {
        const float inv = 1.0f / (8192.0f * 81.0f);
        float m = acc[c] * inv;
        float var = acc[CO + c] * inv - m * m;
        float istd = rsqrtf(var + 1e-5f);
        float sc = istd * gamma[c];
        st[c] = sc;
        st[CO + c] = beta[c] - m * sc;
    }
}

// -------- encoder GEMM: part[ks] = relu(bn3(x3)) @ ewt  (128-img tile) -----
__global__ __launch_bounds__(256) void enc_gemm(const bf16* __restrict__ x3,
        const float* __restrict__ wt, const float* __restrict__ st_g,
        float* __restrict__ part) {
    __shared__ __align__(16) float Ac[32 * 132];   // [kk][im]
    __shared__ __align__(16) float Bc[32 * 132];   // [kk][e]
    __shared__ float st[256];
    int t = threadIdx.x;
    int m0 = blockIdx.x * 128;
    int ks0 = blockIdx.y * 2592;
    st[t & 255] = st_g[t & 255];
    __syncthreads();
    int mg = t & 31, eg = t >> 5;
    int im0 = mg * 4, e0 = eg * 16;
    float acc[4][16];
#pragma unroll
    for (int i = 0; i < 4; i++)
#pragma unroll
        for (int j = 0; j < 16; j++) acc[i][j] = 0.f;

    for (int kc = 0; kc < 2592; kc += 32) {
        int kb = ks0 + kc;
#pragma unroll
        for (int r = 0; r < 2; r++) {
            int i8 = r * 256 + t;          // 512 x 8 bf16 = 128im x 32kk
            int im = i8 >> 2;
            int kk0 = (i8 & 3) * 8;
            uint4 u = *(const uint4*)(x3 + (size_t)(m0 + im) * FLAT + kb + kk0);
            unsigned uu[4] = {u.x, u.y, u.z, u.w};
#pragma unroll
            for (int j = 0; j < 4; j++) {
                int kk = kk0 + j * 2;
                int c0 = (kb + kk) & 127, c1 = (kb + kk + 1) & 127;
                Ac[kk * 132 + im]       = fmaxf(fmaf(bflo(uu[j]), st[c0], st[128 + c0]), 0.f);
                Ac[(kk + 1) * 132 + im] = fmaxf(fmaf(bfhi(uu[j]), st[c1], st[128 + c1]), 0.f);
            }
        }
#pragma unroll
        for (int r = 0; r < 4; r++) {
            int i4 = r * 256 + t;
            int kk = i4 >> 5, e4 = (i4 & 31) * 4;
            *(float4*)&Bc[kk * 132 + e4] = *(const float4*)&wt[(size_t)(kb + kk) * 128 + e4];
        }
        __syncthreads();
#pragma unroll 4
        for (int kk = 0; kk < 32; kk++) {
            float4 av = *(const float4*)&Ac[kk * 132 + im0];
            float aa[4] = {av.x, av.y, av.z, av.w};
#pragma unroll
            for (int j = 0; j < 4; j++) {
                float4 bv = *(const float4*)&Bc[kk * 132 + e0 + j * 4];
                float bbv[4] = {bv.x, bv.y, bv.z, bv.w};
#pragma unroll
                for (int i = 0; i < 4; i++)
#pragma unroll
                    for (int q = 0; q < 4; q++)
                        acc[i][j * 4 + q] = fmaf(aa[i], bbv[q], acc[i][j * 4 + q]);
            }
        }
        __syncthreads();
    }
    float* pp = part + ((size_t)blockIdx.y * NIMG + m0 + im0) * 128 + e0;
#pragma unroll
    for (int i = 0; i < 4; i++)
#pragma unroll
        for (int j = 0; j < 4; j++)
            *(float4*)&pp[(size_t)i * 128 + j * 4] =
                make_float4(acc[i][j*4], acc[i][j*4+1], acc[i][j*4+2], acc[i][j*4+3]);
}

__global__ void enc_reduce(const float* __restrict__ part, const float* __restrict__ encb,
                           float* __restrict__ xE) {
    int i = blockIdx.x * 256 + threadIdx.x;
    if (i < NIMG * 128) {
        float v = part[i] + part[1048576 + i] + part[2097152 + i] + part[3145728 + i];
        xE[i] = v + encb[i & 127];
    }
}

// xT[b][f][n] = xE[b*128+n][f]
__global__ __launch_bounds__(256) void transpose_xe(const float* __restrict__ xE,
                                                    float* __restrict__ xT) {
    int b = blockIdx.x, t = threadIdx.x;
    const float* src = xE + (size_t)b * 16384;
    float* dst = xT + (size_t)b * 16384;
    for (int i = t; i < 16384; i += 256) {
        int n = i & 127, f = i >> 7;
        dst[i] = src[n * 128 + f];
    }
}

// Y[b] = A[b] (128x128) @ S[b] (128x128)
__global__ __launch_bounds__(256) void mm_xs(const float* __restrict__ A,
        const float* __restrict__ S, float* __restrict__ Y) {
    __shared__ __align__(16) float Sc[32 * 132];   // [nn][m]
    __shared__ float Acm[32 * 33];                 // [ff][nn]
    int b = blockIdx.y, f0 = blockIdx.x * 32;
    int t = threadIdx.x;
    int fl = t & 31, mg = t >> 5;
    const float* Ab = A + (size_t)b * 16384;
    const float* Sb = S + (size_t)b * 16384;
    float acc[16];
#pragma unroll
    for (int j = 0; j < 16; j++) acc[j] = 0.f;
    for (int nc = 0; nc < 128; nc += 32) {
#pragma unroll
        for (int r = 0; r < 4; r++) {
            int i4 = r * 256 + t;
            int nn = i4 >> 5, m4 = (i4 & 31) * 4;
            *(float4*)&Sc[nn * 132 + m4] = *(const float4*)&Sb[(size_t)(nc + nn) * 128 + m4];
        }
#pragma unroll
        for (int r = 0; r < 4; r++) {
            int i = r * 256 + t;
            int ff = i >> 5, nn = i & 31;
            Acm[ff * 33 + nn] = Ab[(size_t)(f0 + ff) * 128 + nc + nn];
        }
        __syncthreads();
#pragma unroll 4
        for (int nn = 0; nn < 32; nn++) {
            float a = Acm[fl * 33 + nn];
#pragma unroll
            for (int j = 0; j < 4; j++) {
                float4 s4 = *(const float4*)&Sc[nn * 132 + mg * 16 + j * 4];
                acc[j*4+0] = fmaf(a, s4.x, acc[j*4+0]);
                acc[j*4+1] = fmaf(a, s4.y, acc[j*4+1]);
                acc[j*4+2] = fmaf(a, s4.z, acc[j*4+2]);
                acc[j*4+3] = fmaf(a, s4.w, acc[j*4+3]);
            }
        }
        __syncthreads();
    }
    float* yb = Y + (size_t)b * 16384 + (size_t)(f0 + fl) * 128 + mg * 16;
#pragma unroll
    for (int j = 0; j < 4; j++)
        *(float4*)&yb[j * 4] = make_float4(acc[j*4], acc[j*4+1], acc[j*4+2], acc[j*4+3]);
}

// Out[b][g][n] = relu( sum_f W0[g,f]Z0 + W1 Z1 + W2 Z2 + bias[g] )
__global__ __launch_bounds__(256) void gf_combine(const float* __restrict__ Z0,
        const float* __restrict__ Z1, const float* __restrict__ Z2,
        const float* __restrict__ W, const float* __restrict__ bias,
        float* __restrict__ out) {
    __shared__ __align__(16) float Zc[32 * 132];   // [ff][m]
    __shared__ float Wc[32 * 33];                  // [gg][ff]
    int b = blockIdx.y, g0 = blockIdx.x * 32;
    int t = threadIdx.x;
    int gl = t & 31, mg = t >> 5;
    float acc[16];
    float bb = bias[g0 + gl];
#pragma unroll
    for (int j = 0; j < 16; j++) acc[j] = bb;
    const float* Zs[3] = {Z0 + (size_t)b * 16384, Z1 + (size_t)b * 16384, Z2 + (size_t)b * 16384};
    for (int j3 = 0; j3 < 3; j3++) {
        const float* Zb = Zs[j3];
        const float* Wj = W + j3 * 16384;
        for (int fc = 0; fc < 128; fc += 32) {
#pragma unroll
            for (int r = 0; r < 4; r++) {
                int i4 = r * 256 + t;
                int ff = i4 >> 5, m4 = (i4 & 31) * 4;
                *(float4*)&Zc[ff * 132 + m4] = *(const float4*)&Zb[(size_t)(fc + ff) * 128 + m4];
            }
#pragma unroll
            for (int r = 0; r < 4; r++) {
                int i = r * 256 + t;
                int gg = i >> 5, ff = i & 31;
                Wc[gg * 33 + ff] = Wj[(size_t)(g0 + gg) * 128 + fc + ff];
            }
            __syncthreads();
#pragma unroll 4
            for (int ff = 0; ff < 32; ff++) {
                float w = Wc[gl * 33 + ff];
#pragma unroll
                for (int j = 0; j < 4; j++) {
                    float4 z4 = *(const float4*)&Zc[ff * 132 + mg * 16 + j * 4];
                    acc[j*4+0] = fmaf(w, z4.x, acc[j*4+0]);
                    acc[j*4+1] = fmaf(w, z4.y, acc[j*4+1]);
                    acc[j*4+2] = fmaf(w, z4.z, acc[j*4+2]);
                    acc[j*4+3] = fmaf(w, z4.w, acc[j*4+3]);
                }
            }
            __syncthreads();
        }
    }
    float* ob = out + (size_t)b * 16384 + (size_t)(g0 + gl) * 128 + mg * 16;
#pragma unroll
    for (int j = 0; j < 4; j++)
        *(float4*)&ob[j * 4] = make_float4(fmaxf(acc[j*4], 0.f), fmaxf(acc[j*4+1], 0.f),
                                           fmaxf(acc[j*4+2], 0.f), fmaxf(acc[j*4+3], 0.f));
}

// logits[b,n,a] = sum_g X[b][g][n] * aw[a][g] + ab[a]
__global__ __launch_bounds__(128) void act_kernel(const float* __restrict__ X,
        const float* __restrict__ aw, const float* __restrict__ ab,
        float* __restrict__ out) {
    int b = blockIdx.x, n = threadIdx.x;
    float acc[5];
#pragma unroll
    for (int a = 0; a < 5; a++) acc[a] = ab[a];
    const float* xb = X + (size_t)b * 16384 + n;
#pragma unroll 4
    for (int g = 0; g < 128; g++) {
        float v = xb[(size_t)g * 128];
#pragma unroll
        for (int a = 0; a < 5; a++) acc[a] = fmaf(v, aw[a * 128 + g], acc[a]);
    }
    float* ob = out + ((size_t)b * 128 + n) * 5;
#pragma unroll
    for (int a = 0; a < 5; a++) ob[a] = acc[a];
}

// ---------------------------------------------------------------------------
extern "C" void kernel_launch(void* const* d_in, const int* in_sizes, int n_in,
                              void* d_out, int out_size, void* d_ws, size_t ws_size,
                              hipStream_t stream) {
    const float* states = (const float*)d_in[0];
    const float* gso    = (const float*)d_in[1];
    const float* c1w  = (const float*)d_in[2];
    const float* c1b  = (const float*)d_in[3];
    const float* c1g  = (const float*)d_in[4];
    const float* c1be = (const float*)d_in[5];
    const float* c2w  = (const float*)d_in[6];
    const float* c2b  = (const float*)d_in[7];
    const float* c2g  = (const float*)d_in[8];
    const float* c2be = (const float*)d_in[9];
    const float* c3w  = (const float*)d_in[10];
    const float* c3b  = (const float*)d_in[11];
    const float* c3g  = (const float*)d_in[12];
    const float* c3be = (const float*)d_in[13];
    const float* encw = (const float*)d_in[14];
    const float* encb = (const float*)d_in[15];
    const float* g1w  = (const float*)d_in[16];
    const float* g1b  = (const float*)d_in[17];
    const float* g2w  = (const float*)d_in[18];
    const float* g2b  = (const float*)d_in[19];
    const float* aw   = (const float*)d_in[20];
    const float* ab   = (const float*)d_in[21];
    float* out = (float*)d_out;
    char* ws = (char*)d_ws;

    // ---- layout (peak live ~255.2 MB):
    //   [0, 170MB)        x3   (x1 aliased at offset 0 -- dead before conv3 writes)
    //   [170MB, 255MB)    x2   (after conv3: ewt + all post-conv buffers alias here)
    //   [255MB, +0.4MB)   conv weight transposes + stats
    size_t o = 0;
    auto take = [&](size_t bytes) { size_t r = o; o += (bytes + 255) & ~(size_t)255; return r; };
    const size_t o_x3  = take((size_t)NIMG * 81 * 128 * 2);   // 169,869,312
    const size_t o_x2  = take((size_t)NIMG * 81 * 64 * 2);    //  84,934,656
    const size_t o_w1t = take(27 * 32 * 4);
    const size_t o_w2t = take(288 * 64 * 4);
    const size_t o_w3t = take(576 * 128 * 4);
    const size_t o_acc = take(448 * 4);
    const size_t o_st1 = take(2 * 32 * 4);
    const size_t o_st2 = take(2 * 64 * 4);
    const size_t o_st3 = take(2 * 128 * 4);
    if (ws_size < o) {   // ~243.4 MiB needed
        fill_sentinel<<<(out_size + 255) / 256, 256, 0, stream>>>(out, out_size);
        return;
    }

    const size_t o_x1 = o_x3;                       // x1 (42.5MB) at head of x3 region
    // post-conv buffers alias the x2 region (x2 dead after conv3):
    const size_t o_ewt  = o_x2;                     // 5,308,416
    const size_t o_part = o_x2 + 5308416;           // 16,777,216
    const size_t o_xE   = o_part + 16777216;
    const size_t o_xT   = o_xE + 4194304;
    const size_t o_y1   = o_xT + 4194304;
    const size_t o_y2   = o_y1 + 4194304;
    const size_t o_G1   = o_y2 + 4194304;
    const size_t o_G2   = o_G1 + 4194304;           // ends at o_x2 + 47,251,456 < 84,934,656

    bf16* x1 = (bf16*)(ws + o_x1);
    bf16* x2 = (bf16*)(ws + o_x2);
    bf16* x3 = (bf16*)(ws + o_x3);
    float* w1t = (float*)(ws + o_w1t);
    float* w2t = (float*)(ws + o_w2t);
    float* w3t = (float*)(ws + o_w3t);
    float* acc1 = (float*)(ws + o_acc);
    float* acc2 = acc1 + 64;
    float* acc3 = acc1 + 192;
    float* st1 = (float*)(ws + o_st1);
    float* st2 = (float*)(ws + o_st2);
    float* st3 = (float*)(ws + o_st3);
    float* ewt = (float*)(ws + o_ewt);
    float* partp = (float*)(ws + o_part);
    float* xE = (float*)(ws + o_xE);
    float* xT = (float*)(ws + o_xT);
    float* y1 = (float*)(ws + o_y1);
    float* y2 = (float*)(ws + o_y2);
    float* xG1 = (float*)(ws + o_G1);
    float* xG2 = (float*)(ws + o_G2);

    hipMemsetAsync(ws + o_acc, 0, 448 * 4, stream);
    prep_conv_w<<<64, 256, 0, stream>>>(c1w, c2w, c3w, w1t, w2t, w3t);

    conv1_kernel<<<2048, 128, 0, stream>>>(states, w1t, c1b, x1);
    stats_pass<32><<<256, 256, 0, stream>>>(x1, acc1);
    stats_fin<32><<<1, 32, 0, stream>>>(acc1, c1g, c1be, st1);

    convBN_kernel<32, 64, 2><<<4096, 128, 0, stream>>>(x1, w2t, c2b, st1, x2);
    stats_pass<64><<<256, 256, 0, stream>>>(x2, acc2);
    stats_fin<64><<<1, 64, 0, stream>>>(acc2, c2g, c2be, st2);

    convBN_kernel<64, 128, 1><<<8192, 128, 0, stream>>>(x2, w3t, c3b, st2, x3);
    stats_pass<128><<<256, 256, 0, stream>>>(x3, acc3);
    stats_fin<128><<<1, 128, 0, stream>>>(acc3, c3g, c3be, st3);

    prep_enc_w<<<2048, 256, 0, stream>>>(encw, ewt);   // aliases dead x2
    enc_gemm<<<dim3(64, 4), 256, 0, stream>>>(x3, ewt, st3, partp);
    enc_reduce<<<4096, 256, 0, stream>>>(partp, encb, xE);
    transpose_xe<<<64, 256, 0, stream>>>(xE, xT);

    mm_xs<<<dim3(4, 64), 256, 0, stream>>>(xT, gso, y1);
    mm_xs<<<dim3(4, 64), 256, 0, stream>>>(y1, gso, y2);
    gf_combine<<<dim3(4, 64), 256, 0, stream>>>(xT, y1, y2, g1w, g1b, xG1);

    mm_xs<<<dim3(4, 64), 256, 0, stream>>>(xG1, gso, y1);
    mm_xs<<<dim3(4, 64), 256, 0, stream>>>(y1, gso, y2);
    gf_combine<<<dim3(4, 64), 256, 0, stream>>>(xG1, y1, y2, g2w, g2b, xG2);

    act_kernel<<<64, 128, 0, stream>>>(xG2, aw, ab, out);
}

// Round 3
// 1576.830 us; speedup vs baseline: 1.8112x; 1.8112x over previous
//
#include <hip/hip_runtime.h>
#include <hip/hip_bf16.h>
#include <stdint.h>

// ---------------------------------------------------------------------------
// Network_60163901882451 — round 3: conv2/conv3/encoder on bf16 MFMA.
// Per-output-pixel implicit GEMM: M=images (16/wave), N=oc, K=valid_taps*ci.
// A-frags are direct 16B global loads from [img][px][ci] bf16 (post-BN).
// BN train-mode: conv writes pre-BN bf16 -> stats -> fused scale/shift ->
// elementwise bn_apply in place -> next layer consumes clean bf16.
// ---------------------------------------------------------------------------

#define NIMG 8192
#define NPIX 81
#define FLAT 10368

typedef __hip_bfloat16 bf16;
typedef short bf16x8 __attribute__((ext_vector_type(8)));
typedef float f32x4 __attribute__((ext_vector_type(4)));

__device__ __forceinline__ float bflo(unsigned u) { return __uint_as_float(u << 16); }
__device__ __forceinline__ float bfhi(unsigned u) { return __uint_as_float(u & 0xffff0000u); }
__device__ __forceinline__ unsigned short f2bf(float f) {
    unsigned u = __float_as_uint(f);
    return (unsigned short)((u + 0x7fff + ((u >> 16) & 1)) >> 16);
}

__global__ void fill_sentinel(float* __restrict__ out, int n) {
    int i = blockIdx.x * 256 + threadIdx.x;
    if (i < n) out[i] = 1.0e9f;   // ws_size-too-small signature
}

// ---------------- weight preps ---------------------------------------------
// w1t fp32 [(ci*9+k)][32oc] for direct conv1; w2m/w3m bf16 [oc][tap][ci].
__global__ void prep_w(const float* __restrict__ c1w, const float* __restrict__ c2w,
                       const float* __restrict__ c3w,
                       float* __restrict__ w1t, bf16* __restrict__ w2m,
                       bf16* __restrict__ w3m) {
    int i0 = blockIdx.x * blockDim.x + threadIdx.x;
    int stride = gridDim.x * blockDim.x;
    for (int i = i0; i < 27 * 32; i += stride) w1t[i] = c1w[(i & 31) * 27 + (i >> 5)];
    for (int i = i0; i < 64 * 288; i += stride) {
        int oc = i / 288, r = i - oc * 288, t = r >> 5, ci = r & 31;
        w2m[i] = __float2bfloat16(c2w[oc * 288 + ci * 9 + t]);
    }
    for (int i = i0; i < 128 * 576; i += stride) {
        int oc = i / 576, r = i - oc * 576, t = r >> 6, ci = r & 63;
        w3m[i] = __float2bfloat16(c3w[oc * 576 + ci * 9 + t]);
    }
}

// ewb[e][px*128+ci] = encw[e][ci*81+px]  (bf16; aliases dead x2 -> after conv3)
__global__ void prep_enc(const float* __restrict__ encw, bf16* __restrict__ ewb) {
    int i0 = blockIdx.x * blockDim.x + threadIdx.x;
    int stride = gridDim.x * blockDim.x;
    for (int i = i0; i < 128 * FLAT; i += stride) {
        int e = i / FLAT, r = i - e * FLAT;
        int px = r >> 7, ci = r & 127;
        ewb[i] = __float2bfloat16(encw[(size_t)e * FLAT + ci * 81 + px]);
    }
}

// ---------------- conv1 (direct fp32; tiny) --------------------------------
__device__ __forceinline__ void load_row(const float* __restrict__ p, float* r) {
    float4 a = *(const float4*)p;
    float4 b = *(const float4*)(p + 4);
    float4 c = *(const float4*)(p + 8);
    r[0]=a.x; r[1]=a.y; r[2]=a.z;  r[3]=a.w;
    r[4]=b.x; r[5]=b.y; r[6]=b.z;  r[7]=b.w;
    r[8]=c.x; r[9]=c.y; r[10]=c.z; r[11]=c.w;
}

__device__ __forceinline__ void conv_body(const float* __restrict__ inp, // LDS [11][12]
                                          const float* __restrict__ wv, float* acc) {
    float rb[3][12];
    load_row(inp, rb[0]);
    load_row(inp + 12, rb[1]);
#pragma unroll
    for (int oy = 0; oy < 9; oy++) {
        load_row(inp + (oy + 2) * 12, rb[(oy + 2) % 3]);
#pragma unroll
        for (int ky = 0; ky < 3; ky++) {
            const float* r = rb[(oy + ky) % 3];
#pragma unroll
            for (int ox = 0; ox < 9; ox++) {
                float s = acc[oy * 9 + ox];
                s = fmaf(r[ox + 0], wv[ky * 3 + 0], s);
                s = fmaf(r[ox + 1], wv[ky * 3 + 1], s);
                s = fmaf(r[ox + 2], wv[ky * 3 + 2], s);
                acc[oy * 9 + ox] = s;
            }
        }
    }
}

__global__ __launch_bounds__(128) void conv1_kernel(const float* __restrict__ xin,
        const float* __restrict__ wt, const float* __restrict__ bias,
        bf16* __restrict__ xout) {
    __shared__ __align__(16) float lds[4 * 3 * 132];
    int t = threadIdx.x;
    int img0 = blockIdx.x * 4;
    for (int i = t; i < 4 * 3 * 132; i += 128) lds[i] = 0.f;
    __syncthreads();
    const float* src = xin + (size_t)img0 * 243;
    for (int i = t; i < 4 * 243; i += 128) {
        int il = i / 243, rem = i - il * 243;
        int ci = rem / 81, px = rem - ci * 81;
        lds[(il * 3 + ci) * 132 + (px / 9 + 1) * 12 + (px % 9) + 1] = src[i];
    }
    __syncthreads();
    int oc = t & 31, il = t >> 5;
    const float* base = lds + il * 3 * 132;
    float acc[81];
    float bb = bias[oc];
#pragma unroll
    for (int i = 0; i < 81; i++) acc[i] = bb;
#pragma unroll
    for (int ci = 0; ci < 3; ci++) {
        float wv[9];
#pragma unroll
        for (int k = 0; k < 9; k++) wv[k] = wt[(ci * 9 + k) * 32 + oc];
        conv_body(base + ci * 132, wv, acc);
    }
    bf16* dst = xout + (size_t)(img0 + il) * 81 * 32 + oc;
#pragma unroll
    for (int p = 0; p < 81; p++) dst[p * 32] = __float2bfloat16(acc[p]);
}

// ---------------- MFMA conv: one output pixel per block, 64 imgs/block -----
// xin: post-BN bf16 [img][81][CI]; wm: bf16 [oc][9][CI]; out pre-BN bf16.
template <int CI, int CO>
__global__ __launch_bounds__(256) void conv_mfma(const bf16* __restrict__ xin,
        const bf16* __restrict__ wm, const float* __restrict__ bias,
        bf16* __restrict__ xout) {
    constexpr int NF = CO / 16;
    constexpr int NCH = CI / 32;
    const int bx = blockIdx.x;
    const int p = bx % 81;
    const int ig = bx / 81;
    const int py = p / 9, pxx = p - py * 9;
    const int lane = threadIdx.x & 63;
    const int wv = threadIdx.x >> 6;
    const int m = lane & 15, quad = lane >> 4;
    const long img0 = (long)ig * 64 + wv * 16;

    f32x4 acc[NF];
#pragma unroll
    for (int nf = 0; nf < NF; nf++) {
        float bb = bias[nf * 16 + m];
        acc[nf][0] = bb; acc[nf][1] = bb; acc[nf][2] = bb; acc[nf][3] = bb;
    }
    const bf16* arow = xin + (img0 + m) * (81 * CI) + quad * 8;
    const bf16* brow = wm + (size_t)m * (9 * CI) + quad * 8;

#pragma unroll
    for (int t = 0; t < 9; t++) {
        const int iy = py + t / 3 - 1;
        const int ix = pxx + t % 3 - 1;
        if ((unsigned)iy < 9u && (unsigned)ix < 9u) {
            const int q = iy * 9 + ix;
#pragma unroll
            for (int c = 0; c < NCH; c++) {
                bf16x8 a = *(const bf16x8*)(arow + q * CI + c * 32);
                bf16x8 bfr[NF];
#pragma unroll
                for (int nf = 0; nf < NF; nf++)
                    bfr[nf] = *(const bf16x8*)(brow + (size_t)nf * (16 * 9 * CI) + t * CI + c * 32);
#pragma unroll
                for (int nf = 0; nf < NF; nf++)
                    acc[nf] = __builtin_amdgcn_mfma_f32_16x16x32_bf16(a, bfr[nf], acc[nf], 0, 0, 0);
            }
        }
    }
    // D: col = lane&15 (oc), row = quad*4 + reg (img)
    bf16* orow = xout + (img0 + quad * 4) * (81 * CO) + (size_t)p * CO + m;
#pragma unroll
    for (int nf = 0; nf < NF; nf++)
#pragma unroll
        for (int r = 0; r < 4; r++)
            orow[(size_t)r * (81 * CO) + nf * 16] = __float2bfloat16(acc[nf][r]);
}

// ---------------- encoder: M=img, N=128, K=10368 (k-split 2, oc-split 2) ---
__global__ __launch_bounds__(256) void enc_mfma(const bf16* __restrict__ x3,
        const bf16* __restrict__ ewb, float* __restrict__ part) {
    const int bx = blockIdx.x;
    const int ig = bx & 127, half = (bx >> 7) & 1, nh = bx >> 8;
    const int lane = threadIdx.x & 63, wv = threadIdx.x >> 6;
    const int m = lane & 15, quad = lane >> 4;
    const long img0 = (long)ig * 64 + wv * 16;
    f32x4 acc[4];
#pragma unroll
    for (int nf = 0; nf < 4; nf++) { acc[nf][0]=0.f; acc[nf][1]=0.f; acc[nf][2]=0.f; acc[nf][3]=0.f; }
    const bf16* ar = x3 + (img0 + m) * FLAT + half * 5184 + quad * 8;
    const bf16* br = ewb + (size_t)(nh * 64 + m) * FLAT + half * 5184 + quad * 8;
#pragma unroll 2
    for (int c = 0; c < 162; c++) {
        bf16x8 a = *(const bf16x8*)(ar + c * 32);
#pragma unroll
        for (int nf = 0; nf < 4; nf++) {
            bf16x8 b = *(const bf16x8*)(br + (size_t)nf * (16 * FLAT) + c * 32);
            acc[nf] = __builtin_amdgcn_mfma_f32_16x16x32_bf16(a, b, acc[nf], 0, 0, 0);
        }
    }
    float* pp = part + (size_t)half * (NIMG * 128) + (img0 + quad * 4) * 128 + nh * 64 + m;
#pragma unroll
    for (int nf = 0; nf < 4; nf++)
#pragma unroll
        for (int r = 0; r < 4; r++)
            pp[r * 128 + nf * 16] = acc[nf][r];
}

// ---------------- per-channel sum / sumsq over [663552][CO] bf16 -----------
template <int CO>
__global__ __launch_bounds__(256) void stats_pass(const bf16* __restrict__ x,
                                                  float* __restrict__ acc) {
    constexpr int CH8 = CO / 8;
    constexpr int NG = 256 / CH8;
    __shared__ float ss[2048], sq2[2048];
    int t = threadIdx.x;
    int cg = t % CH8, grp = t / CH8;
    float s[8], q[8];
#pragma unroll
    for (int j = 0; j < 8; j++) { s[j] = 0.f; q[j] = 0.f; }
    const int ROWS = NIMG * 81;
    for (int row = blockIdx.x * NG + grp; row < ROWS; row += gridDim.x * NG) {
        uint4 u = *(const uint4*)(x + (size_t)row * CO + cg * 8);
        float vv[8] = {bflo(u.x), bfhi(u.x), bflo(u.y), bfhi(u.y),
                       bflo(u.z), bfhi(u.z), bflo(u.w), bfhi(u.w)};
#pragma unroll
        for (int j = 0; j < 8; j++) { s[j] += vv[j]; q[j] = fmaf(vv[j], vv[j], q[j]); }
    }
#pragma unroll
    for (int j = 0; j < 8; j++) {
        ss[grp * CO + cg * 8 + j] = s[j];
        sq2[grp * CO + cg * 8 + j] = q[j];
    }
    __syncthreads();
    for (int step = NG / 2; step > 0; step >>= 1) {
        if (grp < step) {
#pragma unroll
            for (int j = 0; j < 8; j++) {
                ss[grp * CO + cg * 8 + j] += ss[(grp + step) * CO + cg * 8 + j];
                sq2[grp * CO + cg * 8 + j] += sq2[(grp + step) * CO + cg * 8 + j];
            }
        }
        __syncthreads();
    }
    if (grp == 0) {
#pragma unroll
        for (int j = 0; j < 8; j++) {
            atomicAdd(&acc[cg * 8 + j], ss[cg * 8 + j]);
            atomicAdd(&acc[CO + cg * 8 + j], sq2[cg * 8 + j]);
        }
    }
}

template <int CO>
__global__ void stats_fin(const float* __restrict__ acc, const float* __restrict__ gamma,
                          const float* __restrict__ beta, float* __restrict__ st) {
    int c = threadIdx.x;
    if (c < CO) {
        const float inv = 1.0f / (8192.0f * 81.0f);
        float m = acc[c] * inv;
        float var = acc[CO + c] * inv - m * m;
        float istd = rsqrtf(var + 1e-5f);
        float sc = istd * gamma[c];
        st[c] = sc;
        st[CO + c] = beta[c] - m * sc;
    }
}

// ---------------- in-place BN+relu apply on bf16 [rows][CO] ----------------
template <int CO>
__global__ __launch_bounds__(256) void bn_apply(bf16* __restrict__ x,
                                                const float* __restrict__ st) {
    const int tid = blockIdx.x * 256 + threadIdx.x;
    const int stride = gridDim.x * 256;
    const int ci0 = (tid * 8) % CO;     // stride*8 divisible by CO -> constant
    float sc[8], sh[8];
#pragma unroll
    for (int j = 0; j < 8; j++) { sc[j] = st[ci0 + j]; sh[j] = st[CO + ci0 + j]; }
    const int TOT8 = NIMG * 81 * CO / 8;
    uint4* xp = (uint4*)x;
    for (int i = tid; i < TOT8; i += stride) {
        uint4 u = xp[i];
        float v[8] = {bflo(u.x), bfhi(u.x), bflo(u.y), bfhi(u.y),
                      bflo(u.z), bfhi(u.z), bflo(u.w), bfhi(u.w)};
        unsigned short us[8];
#pragma unroll
        for (int j = 0; j < 8; j++)
            us[j] = f2bf(fmaxf(fmaf(v[j], sc[j], sh[j]), 0.f));
        uint4 o;
        o.x = us[0] | ((unsigned)us[1] << 16);
        o.y = us[2] | ((unsigned)us[3] << 16);
        o.z = us[4] | ((unsigned)us[5] << 16);
        o.w = us[6] | ((unsigned)us[7] << 16);
        xp[i] = o;
    }
}

__global__ void enc_reduce(const float* __restrict__ part, const float* __restrict__ encb,
                           float* __restrict__ xE) {
    int i = blockIdx.x * 256 + threadIdx.x;
    if (i < NIMG * 128)
        xE[i] = part[i] + part[NIMG * 128 + i] + encb[i & 127];
}

// xT[b][f][n] = xE[b*128+n][f]
__global__ __launch_bounds__(256) void transpose_xe(const float* __restrict__ xE,
                                                    float* __restrict__ xT) {
    int b = blockIdx.x, t = threadIdx.x;
    const float* src = xE + (size_t)b * 16384;
    float* dst = xT + (size_t)b * 16384;
    for (int i = t; i < 16384; i += 256) {
        int n = i & 127, f = i >> 7;
        dst[i] = src[n * 128 + f];
    }
}

// Y[b] = A[b] (128x128) @ S[b] (128x128)
__global__ __launch_bounds__(256) void mm_xs(const float* __restrict__ A,
        const float* __restrict__ S, float* __restrict__ Y) {
    __shared__ __align__(16) float Sc[32 * 132];
    __shared__ float Acm[32 * 33];
    int b = blockIdx.y, f0 = blockIdx.x * 32;
    int t = threadIdx.x;
    int fl = t & 31, mg = t >> 5;
    const float* Ab = A + (size_t)b * 16384;
    const float* Sb = S + (size_t)b * 16384;
    float acc[16];
#pragma unroll
    for (int j = 0; j < 16; j++) acc[j] = 0.f;
    for (int nc = 0; nc < 128; nc += 32) {
#pragma unroll
        for (int r = 0; r < 4; r++) {
            int i4 = r * 256 + t;
            int nn = i4 >> 5, m4 = (i4 & 31) * 4;
            *(float4*)&Sc[nn * 132 + m4] = *(const float4*)&Sb[(size_t)(nc + nn) * 128 + m4];
        }
#pragma unroll
        for (int r = 0; r < 4; r++) {
            int i = r * 256 + t;
            int ff = i >> 5, nn = i & 31;
            Acm[ff * 33 + nn] = Ab[(size_t)(f0 + ff) * 128 + nc + nn];
        }
        __syncthreads();
#pragma unroll 4
        for (int nn = 0; nn < 32; nn++) {
            float a = Acm[fl * 33 + nn];
#pragma unroll
            for (int j = 0; j < 4; j++) {
                float4 s4 = *(const float4*)&Sc[nn * 132 + mg * 16 + j * 4];
                acc[j*4+0] = fmaf(a, s4.x, acc[j*4+0]);
                acc[j*4+1] = fmaf(a, s4.y, acc[j*4+1]);
                acc[j*4+2] = fmaf(a, s4.z, acc[j*4+2]);
                acc[j*4+3] = fmaf(a, s4.w, acc[j*4+3]);
            }
        }
        __syncthreads();
    }
    float* yb = Y + (size_t)b * 16384 + (size_t)(f0 + fl) * 128 + mg * 16;
#pragma unroll
    for (int j = 0; j < 4; j++)
        *(float4*)&yb[j * 4] = make_float4(acc[j*4], acc[j*4+1], acc[j*4+2], acc[j*4+3]);
}

// Out[b][g][n] = relu( sum_f W0[g,f]Z0 + W1 Z1 + W2 Z2 + bias[g] )
__global__ __launch_bounds__(256) void gf_combine(const float* __restrict__ Z0,
        const float* __restrict__ Z1, const float* __restrict__ Z2,
        const float* __restrict__ W, const float* __restrict__ bias,
        float* __restrict__ out) {
    __shared__ __align__(16) float Zc[32 * 132];
    __shared__ float Wc[32 * 33];
    int b = blockIdx.y, g0 = blockIdx.x * 32;
    int t = threadIdx.x;
    int gl = t & 31, mg = t >> 5;
    float acc[16];
    float bb = bias[g0 + gl];
#pragma unroll
    for (int j = 0; j < 16; j++) acc[j] = bb;
    const float* Zs[3] = {Z0 + (size_t)b * 16384, Z1 + (size_t)b * 16384, Z2 + (size_t)b * 16384};
    for (int j3 = 0; j3 < 3; j3++) {
        const float* Zb = Zs[j3];
        const float* Wj = W + j3 * 16384;
        for (int fc = 0; fc < 128; fc += 32) {
#pragma unroll
            for (int r = 0; r < 4; r++) {
                int i4 = r * 256 + t;
                int ff = i4 >> 5, m4 = (i4 & 31) * 4;
                *(float4*)&Zc[ff * 132 + m4] = *(const float4*)&Zb[(size_t)(fc + ff) * 128 + m4];
            }
#pragma unroll
            for (int r = 0; r < 4; r++) {
                int i = r * 256 + t;
                int gg = i >> 5, ff = i & 31;
                Wc[gg * 33 + ff] = Wj[(size_t)(g0 + gg) * 128 + fc + ff];
            }
            __syncthreads();
#pragma unroll 4
            for (int ff = 0; ff < 32; ff++) {
                float w = Wc[gl * 33 + ff];
#pragma unroll
                for (int j = 0; j < 4; j++) {
                    float4 z4 = *(const float4*)&Zc[ff * 132 + mg * 16 + j * 4];
                    acc[j*4+0] = fmaf(w, z4.x, acc[j*4+0]);
                    acc[j*4+1] = fmaf(w, z4.y, acc[j*4+1]);
                    acc[j*4+2] = fmaf(w, z4.z, acc[j*4+2]);
                    acc[j*4+3] = fmaf(w, z4.w, acc[j*4+3]);
                }
            }
            __syncthreads();
        }
    }
    float* ob = out + (size_t)b * 16384 + (size_t)(g0 + gl) * 128 + mg * 16;
#pragma unroll
    for (int j = 0; j < 4; j++)
        *(float4*)&ob[j * 4] = make_float4(fmaxf(acc[j*4], 0.f), fmaxf(acc[j*4+1], 0.f),
                                           fmaxf(acc[j*4+2], 0.f), fmaxf(acc[j*4+3], 0.f));
}

// logits[b,n,a] = sum_g X[b][g][n] * aw[a][g] + ab[a]
__global__ __launch_bounds__(128) void act_kernel(const float* __restrict__ X,
        const float* __restrict__ aw, const float* __restrict__ ab,
        float* __restrict__ out) {
    int b = blockIdx.x, n = threadIdx.x;
    float acc[5];
#pragma unroll
    for (int a = 0; a < 5; a++) acc[a] = ab[a];
    const float* xb = X + (size_t)b * 16384 + n;
#pragma unroll 4
    for (int g = 0; g < 128; g++) {
        float v = xb[(size_t)g * 128];
#pragma unroll
        for (int a = 0; a < 5; a++) acc[a] = fmaf(v, aw[a * 128 + g], acc[a]);
    }
    float* ob = out + ((size_t)b * 128 + n) * 5;
#pragma unroll
    for (int a = 0; a < 5; a++) ob[a] = acc[a];
}

// ---------------------------------------------------------------------------
extern "C" void kernel_launch(void* const* d_in, const int* in_sizes, int n_in,
                              void* d_out, int out_size, void* d_ws, size_t ws_size,
                              hipStream_t stream) {
    const float* states = (const float*)d_in[0];
    const float* gso    = (const float*)d_in[1];
    const float* c1w  = (const float*)d_in[2];
    const float* c1b  = (const float*)d_in[3];
    const float* c1g  = (const float*)d_in[4];
    const float* c1be = (const float*)d_in[5];
    const float* c2w  = (const float*)d_in[6];
    const float* c2b  = (const float*)d_in[7];
    const float* c2g  = (const float*)d_in[8];
    const float* c2be = (const float*)d_in[9];
    const float* c3w  = (const float*)d_in[10];
    const float* c3b  = (const float*)d_in[11];
    const float* c3g  = (const float*)d_in[12];
    const float* c3be = (const float*)d_in[13];
    const float* encw = (const float*)d_in[14];
    const float* encb = (const float*)d_in[15];
    const float* g1w  = (const float*)d_in[16];
    const float* g1b  = (const float*)d_in[17];
    const float* g2w  = (const float*)d_in[18];
    const float* g2b  = (const float*)d_in[19];
    const float* aw   = (const float*)d_in[20];
    const float* ab   = (const float*)d_in[21];
    float* out = (float*)d_out;
    char* ws = (char*)d_ws;

    // layout: [0,170MB) x3 (x1 aliased at head); [170,255MB) x2 (post-conv
    // buffers alias here after conv3); small tail buffers.
    size_t o = 0;
    auto take = [&](size_t bytes) { size_t r = o; o += (bytes + 255) & ~(size_t)255; return r; };
    const size_t o_x3  = take((size_t)NIMG * 81 * 128 * 2);   // 169,869,312
    const size_t o_x2  = take((size_t)NIMG * 81 * 64 * 2);    //  84,934,656
    const size_t o_w1t = take(27 * 32 * 4);
    const size_t o_w2m = take(64 * 288 * 2);
    const size_t o_w3m = take(128 * 576 * 2);
    const size_t o_acc = take(448 * 4);
    const size_t o_st1 = take(2 * 32 * 4);
    const size_t o_st2 = take(2 * 64 * 4);
    const size_t o_st3 = take(2 * 128 * 4);
    if (ws_size < o) {
        fill_sentinel<<<(out_size + 255) / 256, 256, 0, stream>>>(out, out_size);
        return;
    }

    const size_t o_x1 = o_x3;                       // 42.5MB at head of x3 region
    const size_t o_ewb  = o_x2;                     // 2,654,208
    const size_t o_part = o_x2 + 2654208;           // 8,388,608 (2 k-halves)
    const size_t o_xE   = o_part + 8388608;
    const size_t o_xT   = o_xE + 4194304;
    const size_t o_y1   = o_xT + 4194304;
    const size_t o_y2   = o_y1 + 4194304;
    const size_t o_G1   = o_y2 + 4194304;
    const size_t o_G2   = o_G1 + 4194304;           // ends < 85MB region

    bf16* x1 = (bf16*)(ws + o_x1);
    bf16* x2 = (bf16*)(ws + o_x2);
    bf16* x3 = (bf16*)(ws + o_x3);
    float* w1t = (float*)(ws + o_w1t);
    bf16* w2m = (bf16*)(ws + o_w2m);
    bf16* w3m = (bf16*)(ws + o_w3m);
    float* acc1 = (float*)(ws + o_acc);
    float* acc2 = acc1 + 64;
    float* acc3 = acc1 + 192;
    float* st1 = (float*)(ws + o_st1);
    float* st2 = (float*)(ws + o_st2);
    float* st3 = (float*)(ws + o_st3);
    bf16* ewb = (bf16*)(ws + o_ewb);
    float* partp = (float*)(ws + o_part);
    float* xE = (float*)(ws + o_xE);
    float* xT = (float*)(ws + o_xT);
    float* y1 = (float*)(ws + o_y1);
    float* y2 = (float*)(ws + o_y2);
    float* xG1 = (float*)(ws + o_G1);
    float* xG2 = (float*)(ws + o_G2);

    hipMemsetAsync(ws + o_acc, 0, 448 * 4, stream);
    prep_w<<<128, 256, 0, stream>>>(c1w, c2w, c3w, w1t, w2m, w3m);

    conv1_kernel<<<2048, 128, 0, stream>>>(states, w1t, c1b, x1);
    stats_pass<32><<<256, 256, 0, stream>>>(x1, acc1);
    stats_fin<32><<<1, 32, 0, stream>>>(acc1, c1g, c1be, st1);
    bn_apply<32><<<2048, 256, 0, stream>>>(x1, st1);

    conv_mfma<32, 64><<<10368, 256, 0, stream>>>(x1, w2m, c2b, x2);
    stats_pass<64><<<256, 256, 0, stream>>>(x2, acc2);
    stats_fin<64><<<1, 64, 0, stream>>>(acc2, c2g, c2be, st2);
    bn_apply<64><<<2048, 256, 0, stream>>>(x2, st2);

    conv_mfma<64, 128><<<10368, 256, 0, stream>>>(x2, w3m, c3b, x3);
    stats_pass<128><<<256, 256, 0, stream>>>(x3, acc3);
    stats_fin<128><<<1, 128, 0, stream>>>(acc3, c3g, c3be, st3);
    bn_apply<128><<<2048, 256, 0, stream>>>(x3, st3);

    prep_enc<<<2048, 256, 0, stream>>>(encw, ewb);   // aliases dead x2
    enc_mfma<<<512, 256, 0, stream>>>(x3, ewb, partp);
    enc_reduce<<<4096, 256, 0, stream>>>(partp, encb, xE);
    transpose_xe<<<64, 256, 0, stream>>>(xE, xT);

    mm_xs<<<dim3(4, 64), 256, 0, stream>>>(xT, gso, y1);
    mm_xs<<<dim3(4, 64), 256, 0, stream>>>(y1, gso, y2);
    gf_combine<<<dim3(4, 64), 256, 0, stream>>>(xT, y1, y2, g1w, g1b, xG1);

    mm_xs<<<dim3(4, 64), 256, 0, stream>>>(xG1, gso, y1);
    mm_xs<<<dim3(4, 64), 256, 0, stream>>>(y1, gso, y2);
    gf_combine<<<dim3(4, 64), 256, 0, stream>>>(xG1, y1, y2, g2w, g2b, xG2);

    act_kernel<<<64, 128, 0, stream>>>(xG2, aw, ab, out);
}

// Round 4
// 1346.364 us; speedup vs baseline: 2.1213x; 1.1712x over previous
//
#include <hip/hip_runtime.h>
#include <hip/hip_bf16.h>
#include <stdint.h>

// ---------------------------------------------------------------------------
// Network_60163901882451 — round 4: branch-free zero-padded implicit-GEMM
// convs (all 9 taps unconditional, A-frag select-zeroed), 32 imgs/wave,
// hoisted A-loads for MLP. conv3 oc-split 2. Encoder k-split 4, 2 img-sets.
// ---------------------------------------------------------------------------

#define NIMG 8192
#define NPIX 81
#define FLAT 10368

typedef __hip_bfloat16 bf16;
typedef short bf16x8 __attribute__((ext_vector_type(8)));
typedef float f32x4 __attribute__((ext_vector_type(4)));

__device__ __forceinline__ float bflo(unsigned u) { return __uint_as_float(u << 16); }
__device__ __forceinline__ float bfhi(unsigned u) { return __uint_as_float(u & 0xffff0000u); }
__device__ __forceinline__ unsigned short f2bf(float f) {
    unsigned u = __float_as_uint(f);
    return (unsigned short)((u + 0x7fff + ((u >> 16) & 1)) >> 16);
}

__global__ void fill_sentinel(float* __restrict__ out, int n) {
    int i = blockIdx.x * 256 + threadIdx.x;
    if (i < n) out[i] = 1.0e9f;   // ws_size-too-small signature
}

// ---------------- weight preps ---------------------------------------------
__global__ void prep_w(const float* __restrict__ c1w, const float* __restrict__ c2w,
                       const float* __restrict__ c3w,
                       float* __restrict__ w1t, bf16* __restrict__ w2m,
                       bf16* __restrict__ w3m) {
    int i0 = blockIdx.x * blockDim.x + threadIdx.x;
    int stride = gridDim.x * blockDim.x;
    for (int i = i0; i < 27 * 32; i += stride) w1t[i] = c1w[(i & 31) * 27 + (i >> 5)];
    for (int i = i0; i < 64 * 288; i += stride) {
        int oc = i / 288, r = i - oc * 288, t = r >> 5, ci = r & 31;
        w2m[i] = __float2bfloat16(c2w[oc * 288 + ci * 9 + t]);
    }
    for (int i = i0; i < 128 * 576; i += stride) {
        int oc = i / 576, r = i - oc * 576, t = r >> 6, ci = r & 63;
        w3m[i] = __float2bfloat16(c3w[oc * 576 + ci * 9 + t]);
    }
}

// ewb[e][px*128+ci] = encw[e][ci*81+px]
__global__ void prep_enc(const float* __restrict__ encw, bf16* __restrict__ ewb) {
    int i0 = blockIdx.x * blockDim.x + threadIdx.x;
    int stride = gridDim.x * blockDim.x;
    for (int i = i0; i < 128 * FLAT; i += stride) {
        int e = i / FLAT, r = i - e * FLAT;
        int px = r >> 7, ci = r & 127;
        ewb[i] = __float2bfloat16(encw[(size_t)e * FLAT + ci * 81 + px]);
    }
}

// ---------------- conv1 (direct fp32; tiny) --------------------------------
__device__ __forceinline__ void load_row(const float* __restrict__ p, float* r) {
    float4 a = *(const float4*)p;
    float4 b = *(const float4*)(p + 4);
    float4 c = *(const float4*)(p + 8);
    r[0]=a.x; r[1]=a.y; r[2]=a.z;  r[3]=a.w;
    r[4]=b.x; r[5]=b.y; r[6]=b.z;  r[7]=b.w;
    r[8]=c.x; r[9]=c.y; r[10]=c.z; r[11]=c.w;
}

__device__ __forceinline__ void conv_body(const float* __restrict__ inp,
                                          const float* __restrict__ wv, float* acc) {
    float rb[3][12];
    load_row(inp, rb[0]);
    load_row(inp + 12, rb[1]);
#pragma unroll
    for (int oy = 0; oy < 9; oy++) {
        load_row(inp + (oy + 2) * 12, rb[(oy + 2) % 3]);
#pragma unroll
        for (int ky = 0; ky < 3; ky++) {
            const float* r = rb[(oy + ky) % 3];
#pragma unroll
            for (int ox = 0; ox < 9; ox++) {
                float s = acc[oy * 9 + ox];
                s = fmaf(r[ox + 0], wv[ky * 3 + 0], s);
                s = fmaf(r[ox + 1], wv[ky * 3 + 1], s);
                s = fmaf(r[ox + 2], wv[ky * 3 + 2], s);
                acc[oy * 9 + ox] = s;
            }
        }
    }
}

__global__ __launch_bounds__(128) void conv1_kernel(const float* __restrict__ xin,
        const float* __restrict__ wt, const float* __restrict__ bias,
        bf16* __restrict__ xout) {
    __shared__ __align__(16) float lds[4 * 3 * 132];
    int t = threadIdx.x;
    int img0 = blockIdx.x * 4;
    for (int i = t; i < 4 * 3 * 132; i += 128) lds[i] = 0.f;
    __syncthreads();
    const float* src = xin + (size_t)img0 * 243;
    for (int i = t; i < 4 * 243; i += 128) {
        int il = i / 243, rem = i - il * 243;
        int ci = rem / 81, px = rem - ci * 81;
        lds[(il * 3 + ci) * 132 + (px / 9 + 1) * 12 + (px % 9) + 1] = src[i];
    }
    __syncthreads();
    int oc = t & 31, il = t >> 5;
    const float* base = lds + il * 3 * 132;
    float acc[81];
    float bb = bias[oc];
#pragma unroll
    for (int i = 0; i < 81; i++) acc[i] = bb;
#pragma unroll
    for (int ci = 0; ci < 3; ci++) {
        float wv[9];
#pragma unroll
        for (int k = 0; k < 9; k++) wv[k] = wt[(ci * 9 + k) * 32 + oc];
        conv_body(base + ci * 132, wv, acc);
    }
    bf16* dst = xout + (size_t)(img0 + il) * 81 * 32 + oc;
#pragma unroll
    for (int p = 0; p < 81; p++) dst[p * 32] = __float2bfloat16(acc[p]);
}

// ---------------- MFMA conv: branch-free, 128 imgs/block, one pixel --------
// xin: post-BN bf16 [img][81][CI]; wm: bf16 [oc][9tap][CI]; out pre-BN bf16.
// grid: (81*64, COT/(16*NF))
template <int CI, int COT, int NF>
__global__ __launch_bounds__(256) void conv_mfma(const bf16* __restrict__ xin,
        const bf16* __restrict__ wm, const float* __restrict__ bias,
        bf16* __restrict__ xout) {
    constexpr int NCH = CI / 32;
    const int p = blockIdx.x % 81;
    const int ig = blockIdx.x / 81;
    const int oc0 = blockIdx.y * (NF * 16);
    const int py = p / 9, pxx = p - py * 9;
    const int lane = threadIdx.x & 63;
    const int wv = threadIdx.x >> 6;
    const int m = lane & 15, quad = lane >> 4;
    const long img0 = (long)ig * 128 + wv * 32;

    // block-uniform tap validity (zero padding == zeroed A-frag)
    int qt[9];
    bool vt[9];
#pragma unroll
    for (int t = 0; t < 9; t++) {
        int iy = py + t / 3 - 1, ix = pxx + (t % 3) - 1;
        vt[t] = ((unsigned)iy < 9u) && ((unsigned)ix < 9u);
        qt[t] = vt[t] ? iy * 9 + ix : p;   // clamped safe address
    }

    f32x4 acc[2][NF];
#pragma unroll
    for (int nf = 0; nf < NF; nf++) {
        float bb = bias[oc0 + nf * 16 + m];
#pragma unroll
        for (int s = 0; s < 2; s++) {
            acc[s][nf][0] = bb; acc[s][nf][1] = bb;
            acc[s][nf][2] = bb; acc[s][nf][3] = bb;
        }
    }
    const bf16* a0 = xin + (img0 + m) * (81 * CI) + quad * 8;
    const bf16* a1 = a0 + (size_t)16 * (81 * CI);
    const bf16* brow = wm + (size_t)(oc0 + m) * (9 * CI) + quad * 8;
    const bf16x8 zfrag = {0, 0, 0, 0, 0, 0, 0, 0};

#pragma unroll
    for (int c = 0; c < NCH; c++) {
        bf16x8 A0[9], A1[9];
#pragma unroll
        for (int t = 0; t < 9; t++) {      // 18 independent loads -> MLP
            A0[t] = *(const bf16x8*)(a0 + qt[t] * CI + c * 32);
            A1[t] = *(const bf16x8*)(a1 + qt[t] * CI + c * 32);
        }
#pragma unroll
        for (int t = 0; t < 9; t++) {
            bf16x8 av0 = vt[t] ? A0[t] : zfrag;
            bf16x8 av1 = vt[t] ? A1[t] : zfrag;
#pragma unroll
            for (int nf = 0; nf < NF; nf++) {
                bf16x8 b = *(const bf16x8*)(brow + (size_t)nf * (16 * 9 * CI) + t * CI + c * 32);
                acc[0][nf] = __builtin_amdgcn_mfma_f32_16x16x32_bf16(av0, b, acc[0][nf], 0, 0, 0);
                acc[1][nf] = __builtin_amdgcn_mfma_f32_16x16x32_bf16(av1, b, acc[1][nf], 0, 0, 0);
            }
        }
    }
    // D: col = lane&15 (oc), row = quad*4 + reg (img)
#pragma unroll
    for (int s = 0; s < 2; s++) {
        bf16* orow = xout + (img0 + s * 16 + quad * 4) * (81 * COT)
                   + (size_t)p * COT + oc0 + m;
#pragma unroll
        for (int nf = 0; nf < NF; nf++)
#pragma unroll
            for (int r = 0; r < 4; r++)
                orow[(size_t)r * (81 * COT) + nf * 16] = __float2bfloat16(acc[s][nf][r]);
    }
}

// ---------------- encoder: M=img, N=128, K=10368 (k-split 4, oc-split 2) ---
// grid: 64 ig x 4 ks x 2 nh = 512 blocks
__global__ __launch_bounds__(256) void enc_mfma(const bf16* __restrict__ x3,
        const bf16* __restrict__ ewb, float* __restrict__ part) {
    const int bx = blockIdx.x;
    const int ig = bx & 63, ks = (bx >> 6) & 3, nh = bx >> 8;
    const int lane = threadIdx.x & 63, wv = threadIdx.x >> 6;
    const int m = lane & 15, quad = lane >> 4;
    const long img0 = (long)ig * 128 + wv * 32;
    f32x4 acc[2][4];
#pragma unroll
    for (int s = 0; s < 2; s++)
#pragma unroll
        for (int nf = 0; nf < 4; nf++) {
            acc[s][nf][0]=0.f; acc[s][nf][1]=0.f; acc[s][nf][2]=0.f; acc[s][nf][3]=0.f;
        }
    const bf16* ar0 = x3 + (img0 + m) * FLAT + ks * 2592 + quad * 8;
    const bf16* ar1 = ar0 + (size_t)16 * FLAT;
    const bf16* br = ewb + (size_t)(nh * 64 + m) * FLAT + ks * 2592 + quad * 8;
#pragma unroll 3
    for (int c = 0; c < 81; c++) {
        bf16x8 av0 = *(const bf16x8*)(ar0 + c * 32);
        bf16x8 av1 = *(const bf16x8*)(ar1 + c * 32);
#pragma unroll
        for (int nf = 0; nf < 4; nf++) {
            bf16x8 b = *(const bf16x8*)(br + (size_t)nf * (16 * FLAT) + c * 32);
            acc[0][nf] = __builtin_amdgcn_mfma_f32_16x16x32_bf16(av0, b, acc[0][nf], 0, 0, 0);
            acc[1][nf] = __builtin_amdgcn_mfma_f32_16x16x32_bf16(av1, b, acc[1][nf], 0, 0, 0);
        }
    }
#pragma unroll
    for (int s = 0; s < 2; s++) {
        float* pp = part + (size_t)ks * (NIMG * 128)
                  + (img0 + s * 16 + quad * 4) * 128 + nh * 64 + m;
#pragma unroll
        for (int nf = 0; nf < 4; nf++)
#pragma unroll
            for (int r = 0; r < 4; r++)
                pp[r * 128 + nf * 16] = acc[s][nf][r];
    }
}

// ---------------- per-channel sum / sumsq over [663552][CO] bf16 -----------
template <int CO>
__global__ __launch_bounds__(256) void stats_pass(const bf16* __restrict__ x,
                                                  float* __restrict__ acc) {
    constexpr int CH8 = CO / 8;
    constexpr int NG = 256 / CH8;
    __shared__ float ss[2048], sq2[2048];
    int t = threadIdx.x;
    int cg = t % CH8, grp = t / CH8;
    float s[8], q[8];
#pragma unroll
    for (int j = 0; j < 8; j++) { s[j] = 0.f; q[j] = 0.f; }
    const int ROWS = NIMG * 81;
    for (int row = blockIdx.x * NG + grp; row < ROWS; row += gridDim.x * NG) {
        uint4 u = *(const uint4*)(x + (size_t)row * CO + cg * 8);
        float vv[8] = {bflo(u.x), bfhi(u.x), bflo(u.y), bfhi(u.y),
                       bflo(u.z), bfhi(u.z), bflo(u.w), bfhi(u.w)};
#pragma unroll
        for (int j = 0; j < 8; j++) { s[j] += vv[j]; q[j] = fmaf(vv[j], vv[j], q[j]); }
    }
#pragma unroll
    for (int j = 0; j < 8; j++) {
        ss[grp * CO + cg * 8 + j] = s[j];
        sq2[grp * CO + cg * 8 + j] = q[j];
    }
    __syncthreads();
    for (int step = NG / 2; step > 0; step >>= 1) {
        if (grp < step) {
#pragma unroll
            for (int j = 0; j < 8; j++) {
                ss[grp * CO + cg * 8 + j] += ss[(grp + step) * CO + cg * 8 + j];
                sq2[grp * CO + cg * 8 + j] += sq2[(grp + step) * CO + cg * 8 + j];
            }
        }
        __syncthreads();
    }
    if (grp == 0) {
#pragma unroll
        for (int j = 0; j < 8; j++) {
            atomicAdd(&acc[cg * 8 + j], ss[cg * 8 + j]);
            atomicAdd(&acc[CO + cg * 8 + j], sq2[cg * 8 + j]);
        }
    }
}

template <int CO>
__global__ void stats_fin(const float* __restrict__ acc, const float* __restrict__ gamma,
                          const float* __restrict__ beta, float* __restrict__ st) {
    int c = threadIdx.x;
    if (c < CO) {
        const float inv = 1.0f / (8192.0f * 81.0f);
        float m = acc[c] * inv;
        float var = acc[CO + c] * inv - m * m;
        float istd = rsqrtf(var + 1e-5f);
        float sc = istd * gamma[c];
        st[c] = sc;
        st[CO + c] = beta[c] - m * sc;
    }
}

// ---------------- in-place BN+relu apply on bf16 [rows][CO] ----------------
template <int CO>
__global__ __launch_bounds__(256) void bn_apply(bf16* __restrict__ x,
                                                const float* __restrict__ st) {
    const int tid = blockIdx.x * 256 + threadIdx.x;
    const int stride = gridDim.x * 256;
    const int ci0 = (tid * 8) % CO;
    float sc[8], sh[8];
#pragma unroll
    for (int j = 0; j < 8; j++) { sc[j] = st[ci0 + j]; sh[j] = st[CO + ci0 + j]; }
    const int TOT8 = NIMG * 81 * CO / 8;
    uint4* xp = (uint4*)x;
    for (int i = tid; i < TOT8; i += stride) {
        uint4 u = xp[i];
        float v[8] = {bflo(u.x), bfhi(u.x), bflo(u.y), bfhi(u.y),
                      bflo(u.z), bfhi(u.z), bflo(u.w), bfhi(u.w)};
        unsigned short us[8];
#pragma unroll
        for (int j = 0; j < 8; j++)
            us[j] = f2bf(fmaxf(fmaf(v[j], sc[j], sh[j]), 0.f));
        uint4 o;
        o.x = us[0] | ((unsigned)us[1] << 16);
        o.y = us[2] | ((unsigned)us[3] << 16);
        o.z = us[4] | ((unsigned)us[5] << 16);
        o.w = us[6] | ((unsigned)us[7] << 16);
        xp[i] = o;
    }
}

__global__ void enc_reduce(const float* __restrict__ part, const float* __restrict__ encb,
                           float* __restrict__ xE) {
    int i = blockIdx.x * 256 + threadIdx.x;
    const int NP = NIMG * 128;
    if (i < NP)
        xE[i] = part[i] + part[NP + i] + part[2 * NP + i] + part[3 * NP + i] + encb[i & 127];
}

// xT[b][f][n] = xE[b*128+n][f]
__global__ __launch_bounds__(256) void transpose_xe(const float* __restrict__ xE,
                                                    float* __restrict__ xT) {
    int b = blockIdx.x, t = threadIdx.x;
    const float* src = xE + (size_t)b * 16384;
    float* dst = xT + (size_t)b * 16384;
    for (int i = t; i < 16384; i += 256) {
        int n = i & 127, f = i >> 7;
        dst[i] = src[n * 128 + f];
    }
}

// Y[b] = A[b] (128x128) @ S[b] (128x128)
__global__ __launch_bounds__(256) void mm_xs(const float* __restrict__ A,
        const float* __restrict__ S, float* __restrict__ Y) {
    __shared__ __align__(16) float Sc[32 * 132];
    __shared__ float Acm[32 * 33];
    int b = blockIdx.y, f0 = blockIdx.x * 32;
    int t = threadIdx.x;
    int fl = t & 31, mg = t >> 5;
    const float* Ab = A + (size_t)b * 16384;
    const float* Sb = S + (size_t)b * 16384;
    float acc[16];
#pragma unroll
    for (int j = 0; j < 16; j++) acc[j] = 0.f;
    for (int nc = 0; nc < 128; nc += 32) {
#pragma unroll
        for (int r = 0; r < 4; r++) {
            int i4 = r * 256 + t;
            int nn = i4 >> 5, m4 = (i4 & 31) * 4;
            *(float4*)&Sc[nn * 132 + m4] = *(const float4*)&Sb[(size_t)(nc + nn) * 128 + m4];
        }
#pragma unroll
        for (int r = 0; r < 4; r++) {
            int i = r * 256 + t;
            int ff = i >> 5, nn = i & 31;
            Acm[ff * 33 + nn] = Ab[(size_t)(f0 + ff) * 128 + nc + nn];
        }
        __syncthreads();
#pragma unroll 4
        for (int nn = 0; nn < 32; nn++) {
            float a = Acm[fl * 33 + nn];
#pragma unroll
            for (int j = 0; j < 4; j++) {
                float4 s4 = *(const float4*)&Sc[nn * 132 + mg * 16 + j * 4];
                acc[j*4+0] = fmaf(a, s4.x, acc[j*4+0]);
                acc[j*4+1] = fmaf(a, s4.y, acc[j*4+1]);
                acc[j*4+2] = fmaf(a, s4.z, acc[j*4+2]);
                acc[j*4+3] = fmaf(a, s4.w, acc[j*4+3]);
            }
        }
        __syncthreads();
    }
    float* yb = Y + (size_t)b * 16384 + (size_t)(f0 + fl) * 128 + mg * 16;
#pragma unroll
    for (int j = 0; j < 4; j++)
        *(float4*)&yb[j * 4] = make_float4(acc[j*4], acc[j*4+1], acc[j*4+2], acc[j*4+3]);
}

// Out[b][g][n] = relu( sum_f W0[g,f]Z0 + W1 Z1 + W2 Z2 + bias[g] )
__global__ __launch_bounds__(256) void gf_combine(const float* __restrict__ Z0,
        const float* __restrict__ Z1, const float* __restrict__ Z2,
        const float* __restrict__ W, const float* __restrict__ bias,
        float* __restrict__ out) {
    __shared__ __align__(16) float Zc[32 * 132];
    __shared__ float Wc[32 * 33];
    int b = blockIdx.y, g0 = blockIdx.x * 32;
    int t = threadIdx.x;
    int gl = t & 31, mg = t >> 5;
    float acc[16];
    float bb = bias[g0 + gl];
#pragma unroll
    for (int j = 0; j < 16; j++) acc[j] = bb;
    const float* Zs[3] = {Z0 + (size_t)b * 16384, Z1 + (size_t)b * 16384, Z2 + (size_t)b * 16384};
    for (int j3 = 0; j3 < 3; j3++) {
        const float* Zb = Zs[j3];
        const float* Wj = W + j3 * 16384;
        for (int fc = 0; fc < 128; fc += 32) {
#pragma unroll
            for (int r = 0; r < 4; r++) {
                int i4 = r * 256 + t;
                int ff = i4 >> 5, m4 = (i4 & 31) * 4;
                *(float4*)&Zc[ff * 132 + m4] = *(const float4*)&Zb[(size_t)(fc + ff) * 128 + m4];
            }
#pragma unroll
            for (int r = 0; r < 4; r++) {
                int i = r * 256 + t;
                int gg = i >> 5, ff = i & 31;
                Wc[gg * 33 + ff] = Wj[(size_t)(g0 + gg) * 128 + fc + ff];
            }
            __syncthreads();
#pragma unroll 4
            for (int ff = 0; ff < 32; ff++) {
                float w = Wc[gl * 33 + ff];
#pragma unroll
                for (int j = 0; j < 4; j++) {
                    float4 z4 = *(const float4*)&Zc[ff * 132 + mg * 16 + j * 4];
                    acc[j*4+0] = fmaf(w, z4.x, acc[j*4+0]);
                    acc[j*4+1] = fmaf(w, z4.y, acc[j*4+1]);
                    acc[j*4+2] = fmaf(w, z4.z, acc[j*4+2]);
                    acc[j*4+3] = fmaf(w, z4.w, acc[j*4+3]);
                }
            }
            __syncthreads();
        }
    }
    float* ob = out + (size_t)b * 16384 + (size_t)(g0 + gl) * 128 + mg * 16;
#pragma unroll
    for (int j = 0; j < 4; j++)
        *(float4*)&ob[j * 4] = make_float4(fmaxf(acc[j*4], 0.f), fmaxf(acc[j*4+1], 0.f),
                                           fmaxf(acc[j*4+2], 0.f), fmaxf(acc[j*4+3], 0.f));
}

// logits[b,n,a] = sum_g X[b][g][n] * aw[a][g] + ab[a]
__global__ __launch_bounds__(128) void act_kernel(const float* __restrict__ X,
        const float* __restrict__ aw, const float* __restrict__ ab,
        float* __restrict__ out) {
    int b = blockIdx.x, n = threadIdx.x;
    float acc[5];
#pragma unroll
    for (int a = 0; a < 5; a++) acc[a] = ab[a];
    const float* xb = X + (size_t)b * 16384 + n;
#pragma unroll 4
    for (int g = 0; g < 128; g++) {
        float v = xb[(size_t)g * 128];
#pragma unroll
        for (int a = 0; a < 5; a++) acc[a] = fmaf(v, aw[a * 128 + g], acc[a]);
    }
    float* ob = out + ((size_t)b * 128 + n) * 5;
#pragma unroll
    for (int a = 0; a < 5; a++) ob[a] = acc[a];
}

// ---------------------------------------------------------------------------
extern "C" void kernel_launch(void* const* d_in, const int* in_sizes, int n_in,
                              void* d_out, int out_size, void* d_ws, size_t ws_size,
                              hipStream_t stream) {
    const float* states = (const float*)d_in[0];
    const float* gso    = (const float*)d_in[1];
    const float* c1w  = (const float*)d_in[2];
    const float* c1b  = (const float*)d_in[3];
    const float* c1g  = (const float*)d_in[4];
    const float* c1be = (const float*)d_in[5];
    const float* c2w  = (const float*)d_in[6];
    const float* c2b  = (const float*)d_in[7];
    const float* c2g  = (const float*)d_in[8];
    const float* c2be = (const float*)d_in[9];
    const float* c3w  = (const float*)d_in[10];
    const float* c3b  = (const float*)d_in[11];
    const float* c3g  = (const float*)d_in[12];
    const float* c3be = (const float*)d_in[13];
    const float* encw = (const float*)d_in[14];
    const float* encb = (const float*)d_in[15];
    const float* g1w  = (const float*)d_in[16];
    const float* g1b  = (const float*)d_in[17];
    const float* g2w  = (const float*)d_in[18];
    const float* g2b  = (const float*)d_in[19];
    const float* aw   = (const float*)d_in[20];
    const float* ab   = (const float*)d_in[21];
    float* out = (float*)d_out;
    char* ws = (char*)d_ws;

    size_t o = 0;
    auto take = [&](size_t bytes) { size_t r = o; o += (bytes + 255) & ~(size_t)255; return r; };
    const size_t o_x3  = take((size_t)NIMG * 81 * 128 * 2);   // 169,869,312
    const size_t o_x2  = take((size_t)NIMG * 81 * 64 * 2);    //  84,934,656
    const size_t o_w1t = take(27 * 32 * 4);
    const size_t o_w2m = take(64 * 288 * 2);
    const size_t o_w3m = take(128 * 576 * 2);
    const size_t o_acc = take(448 * 4);
    const size_t o_st1 = take(2 * 32 * 4);
    const size_t o_st2 = take(2 * 64 * 4);
    const size_t o_st3 = take(2 * 128 * 4);
    if (ws_size < o) {
        fill_sentinel<<<(out_size + 255) / 256, 256, 0, stream>>>(out, out_size);
        return;
    }

    const size_t o_x1 = o_x3;                       // x1 at head of x3 region
    const size_t o_ewb  = o_x2;                     // 2,654,208 (aliases dead x2)
    const size_t o_part = o_x2 + 2654208;           // 16,777,216 (4 k-split partials)
    const size_t o_xE   = o_part + 16777216;
    const size_t o_xT   = o_xE + 4194304;
    const size_t o_y1   = o_xT + 4194304;
    const size_t o_y2   = o_y1 + 4194304;
    const size_t o_G1   = o_y2 + 4194304;
    const size_t o_G2   = o_G1 + 4194304;           // ends ~44.6MB < 85MB region

    bf16* x1 = (bf16*)(ws + o_x1);
    bf16* x2 = (bf16*)(ws + o_x2);
    bf16* x3 = (bf16*)(ws + o_x3);
    float* w1t = (float*)(ws + o_w1t);
    bf16* w2m = (bf16*)(ws + o_w2m);
    bf16* w3m = (bf16*)(ws + o_w3m);
    float* acc1 = (float*)(ws + o_acc);
    float* acc2 = acc1 + 64;
    float* acc3 = acc1 + 192;
    float* st1 = (float*)(ws + o_st1);
    float* st2 = (float*)(ws + o_st2);
    float* st3 = (float*)(ws + o_st3);
    bf16* ewb = (bf16*)(ws + o_ewb);
    float* partp = (float*)(ws + o_part);
    float* xE = (float*)(ws + o_xE);
    float* xT = (float*)(ws + o_xT);
    float* y1 = (float*)(ws + o_y1);
    float* y2 = (float*)(ws + o_y2);
    float* xG1 = (float*)(ws + o_G1);
    float* xG2 = (float*)(ws + o_G2);

    hipMemsetAsync(ws + o_acc, 0, 448 * 4, stream);
    prep_w<<<128, 256, 0, stream>>>(c1w, c2w, c3w, w1t, w2m, w3m);

    conv1_kernel<<<2048, 128, 0, stream>>>(states, w1t, c1b, x1);
    stats_pass<32><<<256, 256, 0, stream>>>(x1, acc1);
    stats_fin<32><<<1, 32, 0, stream>>>(acc1, c1g, c1be, st1);
    bn_apply<32><<<2048, 256, 0, stream>>>(x1, st1);

    conv_mfma<32, 64, 4><<<dim3(5184, 1), 256, 0, stream>>>(x1, w2m, c2b, x2);
    stats_pass<64><<<256, 256, 0, stream>>>(x2, acc2);
    stats_fin<64><<<1, 64, 0, stream>>>(acc2, c2g, c2be, st2);
    bn_apply<64><<<2048, 256, 0, stream>>>(x2, st2);

    conv_mfma<64, 128, 4><<<dim3(5184, 2), 256, 0, stream>>>(x2, w3m, c3b, x3);
    stats_pass<128><<<256, 256, 0, stream>>>(x3, acc3);
    stats_fin<128><<<1, 128, 0, stream>>>(acc3, c3g, c3be, st3);
    bn_apply<128><<<2048, 256, 0, stream>>>(x3, st3);

    prep_enc<<<2048, 256, 0, stream>>>(encw, ewb);
    enc_mfma<<<512, 256, 0, stream>>>(x3, ewb, partp);
    enc_reduce<<<4096, 256, 0, stream>>>(partp, encb, xE);
    transpose_xe<<<64, 256, 0, stream>>>(xE, xT);

    mm_xs<<<dim3(4, 64), 256, 0, stream>>>(xT, gso, y1);
    mm_xs<<<dim3(4, 64), 256, 0, stream>>>(y1, gso, y2);
    gf_combine<<<dim3(4, 64), 256, 0, stream>>>(xT, y1, y2, g1w, g1b, xG1);

    mm_xs<<<dim3(4, 64), 256, 0, stream>>>(xG1, gso, y1);
    mm_xs<<<dim3(4, 64), 256, 0, stream>>>(y1, gso, y2);
    gf_combine<<<dim3(4, 64), 256, 0, stream>>>(xG1, y1, y2, g2w, g2b, xG2);

    act_kernel<<<64, 128, 0, stream>>>(xG2, aw, ab, out);
}

// Round 5
// 1325.247 us; speedup vs baseline: 2.1551x; 1.0159x over previous
//
#include <hip/hip_runtime.h>
#include <hip/hip_bf16.h>
#include <stdint.h>

// ---------------------------------------------------------------------------
// Network_60163901882451 — round 5: XCD-aware block swizzle on the MFMA
// convs + encoder. Each XCD gets a contiguous 8-image-group slice (pixel /
// oc-half varying fastest) so the 9x tap-reuse hits the per-XCD L2 instead
// of re-fetching from HBM (round 4 showed exactly 8x over-fetch).
// ---------------------------------------------------------------------------

#define NIMG 8192
#define NPIX 81
#define FLAT 10368

typedef __hip_bfloat16 bf16;
typedef short bf16x8 __attribute__((ext_vector_type(8)));
typedef float f32x4 __attribute__((ext_vector_type(4)));

__device__ __forceinline__ float bflo(unsigned u) { return __uint_as_float(u << 16); }
__device__ __forceinline__ float bfhi(unsigned u) { return __uint_as_float(u & 0xffff0000u); }
__device__ __forceinline__ unsigned short f2bf(float f) {
    unsigned u = __float_as_uint(f);
    return (unsigned short)((u + 0x7fff + ((u >> 16) & 1)) >> 16);
}

__global__ void fill_sentinel(float* __restrict__ out, int n) {
    int i = blockIdx.x * 256 + threadIdx.x;
    if (i < n) out[i] = 1.0e9f;   // ws_size-too-small signature
}

// ---------------- weight preps ---------------------------------------------
__global__ void prep_w(const float* __restrict__ c1w, const float* __restrict__ c2w,
                       const float* __restrict__ c3w,
                       float* __restrict__ w1t, bf16* __restrict__ w2m,
                       bf16* __restrict__ w3m) {
    int i0 = blockIdx.x * blockDim.x + threadIdx.x;
    int stride = gridDim.x * blockDim.x;
    for (int i = i0; i < 27 * 32; i += stride) w1t[i] = c1w[(i & 31) * 27 + (i >> 5)];
    for (int i = i0; i < 64 * 288; i += stride) {
        int oc = i / 288, r = i - oc * 288, t = r >> 5, ci = r & 31;
        w2m[i] = __float2bfloat16(c2w[oc * 288 + ci * 9 + t]);
    }
    for (int i = i0; i < 128 * 576; i += stride) {
        int oc = i / 576, r = i - oc * 576, t = r >> 6, ci = r & 63;
        w3m[i] = __float2bfloat16(c3w[oc * 576 + ci * 9 + t]);
    }
}

// ewb[e][px*128+ci] = encw[e][ci*81+px]
__global__ void prep_enc(const float* __restrict__ encw, bf16* __restrict__ ewb) {
    int i0 = blockIdx.x * blockDim.x + threadIdx.x;
    int stride = gridDim.x * blockDim.x;
    for (int i = i0; i < 128 * FLAT; i += stride) {
        int e = i / FLAT, r = i - e * FLAT;
        int px = r >> 7, ci = r & 127;
        ewb[i] = __float2bfloat16(encw[(size_t)e * FLAT + ci * 81 + px]);
    }
}

// ---------------- conv1 (direct fp32; tiny) --------------------------------
__device__ __forceinline__ void load_row(const float* __restrict__ p, float* r) {
    float4 a = *(const float4*)p;
    float4 b = *(const float4*)(p + 4);
    float4 c = *(const float4*)(p + 8);
    r[0]=a.x; r[1]=a.y; r[2]=a.z;  r[3]=a.w;
    r[4]=b.x; r[5]=b.y; r[6]=b.z;  r[7]=b.w;
    r[8]=c.x; r[9]=c.y; r[10]=c.z; r[11]=c.w;
}

__device__ __forceinline__ void conv_body(const float* __restrict__ inp,
                                          const float* __restrict__ wv, float* acc) {
    float rb[3][12];
    load_row(inp, rb[0]);
    load_row(inp + 12, rb[1]);
#pragma unroll
    for (int oy = 0; oy < 9; oy++) {
        load_row(inp + (oy + 2) * 12, rb[(oy + 2) % 3]);
#pragma unroll
        for (int ky = 0; ky < 3; ky++) {
            const float* r = rb[(oy + ky) % 3];
#pragma unroll
            for (int ox = 0; ox < 9; ox++) {
                float s = acc[oy * 9 + ox];
                s = fmaf(r[ox + 0], wv[ky * 3 + 0], s);
                s = fmaf(r[ox + 1], wv[ky * 3 + 1], s);
                s = fmaf(r[ox + 2], wv[ky * 3 + 2], s);
                acc[oy * 9 + ox] = s;
            }
        }
    }
}

__global__ __launch_bounds__(128) void conv1_kernel(const float* __restrict__ xin,
        const float* __restrict__ wt, const float* __restrict__ bias,
        bf16* __restrict__ xout) {
    __shared__ __align__(16) float lds[4 * 3 * 132];
    int t = threadIdx.x;
    int img0 = blockIdx.x * 4;
    for (int i = t; i < 4 * 3 * 132; i += 128) lds[i] = 0.f;
    __syncthreads();
    const float* src = xin + (size_t)img0 * 243;
    for (int i = t; i < 4 * 243; i += 128) {
        int il = i / 243, rem = i - il * 243;
        int ci = rem / 81, px = rem - ci * 81;
        lds[(il * 3 + ci) * 132 + (px / 9 + 1) * 12 + (px % 9) + 1] = src[i];
    }
    __syncthreads();
    int oc = t & 31, il = t >> 5;
    const float* base = lds + il * 3 * 132;
    float acc[81];
    float bb = bias[oc];
#pragma unroll
    for (int i = 0; i < 81; i++) acc[i] = bb;
#pragma unroll
    for (int ci = 0; ci < 3; ci++) {
        float wv[9];
#pragma unroll
        for (int k = 0; k < 9; k++) wv[k] = wt[(ci * 9 + k) * 32 + oc];
        conv_body(base + ci * 132, wv, acc);
    }
    bf16* dst = xout + (size_t)(img0 + il) * 81 * 32 + oc;
#pragma unroll
    for (int p = 0; p < 81; p++) dst[p * 32] = __float2bfloat16(acc[p]);
}

// ---------------- MFMA conv: branch-free, 128 imgs/block, one pixel --------
// xin: post-BN bf16 [img][81][CI]; wm: bf16 [oc][9tap][CI]; out pre-BN bf16.
// 1-D grid of 81*64*OCS blocks; XCD-swizzled: xcd = lin&7 owns 8 ig groups,
// within slice pixel varies next, oc-half fastest (perfect A sharing).
template <int CI, int COT, int NF, int OCS>
__global__ __launch_bounds__(256) void conv_mfma(const bf16* __restrict__ xin,
        const bf16* __restrict__ wm, const float* __restrict__ bias,
        bf16* __restrict__ xout) {
    constexpr int NCH = CI / 32;
    constexpr int PER = 81 * OCS;        // blocks per ig group
    const int lin = blockIdx.x;
    const int xcd = lin & 7;
    const int slot = lin >> 3;
    const int igl = slot / PER;
    const int rem = slot - igl * PER;
    const int p = rem / OCS;
    const int ob = rem - p * OCS;
    const int ig = xcd * 8 + igl;        // 64 ig groups, 8 per XCD
    const int oc0 = ob * (NF * 16);
    const int py = p / 9, pxx = p - py * 9;
    const int lane = threadIdx.x & 63;
    const int wv = threadIdx.x >> 6;
    const int m = lane & 15, quad = lane >> 4;
    const long img0 = (long)ig * 128 + wv * 32;

    // block-uniform tap validity (zero padding == zeroed A-frag)
    int qt[9];
    bool vt[9];
#pragma unroll
    for (int t = 0; t < 9; t++) {
        int iy = py + t / 3 - 1, ix = pxx + (t % 3) - 1;
        vt[t] = ((unsigned)iy < 9u) && ((unsigned)ix < 9u);
        qt[t] = vt[t] ? iy * 9 + ix : p;   // clamped safe address
    }

    f32x4 acc[2][NF];
#pragma unroll
    for (int nf = 0; nf < NF; nf++) {
        float bb = bias[oc0 + nf * 16 + m];
#pragma unroll
        for (int s = 0; s < 2; s++) {
            acc[s][nf][0] = bb; acc[s][nf][1] = bb;
            acc[s][nf][2] = bb; acc[s][nf][3] = bb;
        }
    }
    const bf16* a0 = xin + (img0 + m) * (81 * CI) + quad * 8;
    const bf16* a1 = a0 + (size_t)16 * (81 * CI);
    const bf16* brow = wm + (size_t)(oc0 + m) * (9 * CI) + quad * 8;
    const bf16x8 zfrag = {0, 0, 0, 0, 0, 0, 0, 0};

#pragma unroll
    for (int c = 0; c < NCH; c++) {
        bf16x8 A0[9], A1[9];
#pragma unroll
        for (int t = 0; t < 9; t++) {      // 18 independent loads -> MLP
            A0[t] = *(const bf16x8*)(a0 + qt[t] * CI + c * 32);
            A1[t] = *(const bf16x8*)(a1 + qt[t] * CI + c * 32);
        }
#pragma unroll
        for (int t = 0; t < 9; t++) {
            bf16x8 av0 = vt[t] ? A0[t] : zfrag;
            bf16x8 av1 = vt[t] ? A1[t] : zfrag;
#pragma unroll
            for (int nf = 0; nf < NF; nf++) {
                bf16x8 b = *(const bf16x8*)(brow + (size_t)nf * (16 * 9 * CI) + t * CI + c * 32);
                acc[0][nf] = __builtin_amdgcn_mfma_f32_16x16x32_bf16(av0, b, acc[0][nf], 0, 0, 0);
                acc[1][nf] = __builtin_amdgcn_mfma_f32_16x16x32_bf16(av1, b, acc[1][nf], 0, 0, 0);
            }
        }
    }
    // D: col = lane&15 (oc), row = quad*4 + reg (img)
#pragma unroll
    for (int s = 0; s < 2; s++) {
        bf16* orow = xout + (img0 + s * 16 + quad * 4) * (81 * COT)
                   + (size_t)p * COT + oc0 + m;
#pragma unroll
        for (int nf = 0; nf < NF; nf++)
#pragma unroll
            for (int r = 0; r < 4; r++)
                orow[(size_t)r * (81 * COT) + nf * 16] = __float2bfloat16(acc[s][nf][r]);
    }
}

// ---------------- encoder: M=img, N=128, K=10368 (k-split 4, oc-split 2) ---
// 512 blocks, XCD-swizzled: xcd owns 8 ig; within slice ks next, nh fastest.
__global__ __launch_bounds__(256) void enc_mfma(const bf16* __restrict__ x3,
        const bf16* __restrict__ ewb, float* __restrict__ part) {
    const int lin = blockIdx.x;
    const int xcd = lin & 7;
    const int slot = lin >> 3;           // 64 per XCD
    const int igl = slot >> 3;
    const int r2 = slot & 7;
    const int ks = r2 >> 1;
    const int nh = r2 & 1;
    const int ig = xcd * 8 + igl;
    const int lane = threadIdx.x & 63, wv = threadIdx.x >> 6;
    const int m = lane & 15, quad = lane >> 4;
    const long img0 = (long)ig * 128 + wv * 32;
    f32x4 acc[2][4];
#pragma unroll
    for (int s = 0; s < 2; s++)
#pragma unroll
        for (int nf = 0; nf < 4; nf++) {
            acc[s][nf][0]=0.f; acc[s][nf][1]=0.f; acc[s][nf][2]=0.f; acc[s][nf][3]=0.f;
        }
    const bf16* ar0 = x3 + (img0 + m) * FLAT + ks * 2592 + quad * 8;
    const bf16* ar1 = ar0 + (size_t)16 * FLAT;
    const bf16* br = ewb + (size_t)(nh * 64 + m) * FLAT + ks * 2592 + quad * 8;
#pragma unroll 3
    for (int c = 0; c < 81; c++) {
        bf16x8 av0 = *(const bf16x8*)(ar0 + c * 32);
        bf16x8 av1 = *(const bf16x8*)(ar1 + c * 32);
#pragma unroll
        for (int nf = 0; nf < 4; nf++) {
            bf16x8 b = *(const bf16x8*)(br + (size_t)nf * (16 * FLAT) + c * 32);
            acc[0][nf] = __builtin_amdgcn_mfma_f32_16x16x32_bf16(av0, b, acc[0][nf], 0, 0, 0);
            acc[1][nf] = __builtin_amdgcn_mfma_f32_16x16x32_bf16(av1, b, acc[1][nf], 0, 0, 0);
        }
    }
#pragma unroll
    for (int s = 0; s < 2; s++) {
        float* pp = part + (size_t)ks * (NIMG * 128)
                  + (img0 + s * 16 + quad * 4) * 128 + nh * 64 + m;
#pragma unroll
        for (int nf = 0; nf < 4; nf++)
#pragma unroll
            for (int r = 0; r < 4; r++)
                pp[r * 128 + nf * 16] = acc[s][nf][r];
    }
}

// ---------------- per-channel sum / sumsq over [663552][CO] bf16 -----------
template <int CO>
__global__ __launch_bounds__(256) void stats_pass(const bf16* __restrict__ x,
                                                  float* __restrict__ acc) {
    constexpr int CH8 = CO / 8;
    constexpr int NG = 256 / CH8;
    __shared__ float ss[2048], sq2[2048];
    int t = threadIdx.x;
    int cg = t % CH8, grp = t / CH8;
    float s[8], q[8];
#pragma unroll
    for (int j = 0; j < 8; j++) { s[j] = 0.f; q[j] = 0.f; }
    const int ROWS = NIMG * 81;
    for (int row = blockIdx.x * NG + grp; row < ROWS; row += gridDim.x * NG) {
        uint4 u = *(const uint4*)(x + (size_t)row * CO + cg * 8);
        float vv[8] = {bflo(u.x), bfhi(u.x), bflo(u.y), bfhi(u.y),
                       bflo(u.z), bfhi(u.z), bflo(u.w), bfhi(u.w)};
#pragma unroll
        for (int j = 0; j < 8; j++) { s[j] += vv[j]; q[j] = fmaf(vv[j], vv[j], q[j]); }
    }
#pragma unroll
    for (int j = 0; j < 8; j++) {
        ss[grp * CO + cg * 8 + j] = s[j];
        sq2[grp * CO + cg * 8 + j] = q[j];
    }
    __syncthreads();
    for (int step = NG / 2; step > 0; step >>= 1) {
        if (grp < step) {
#pragma unroll
            for (int j = 0; j < 8; j++) {
                ss[grp * CO + cg * 8 + j] += ss[(grp + step) * CO + cg * 8 + j];
                sq2[grp * CO + cg * 8 + j] += sq2[(grp + step) * CO + cg * 8 + j];
            }
        }
        __syncthreads();
    }
    if (grp == 0) {
#pragma unroll
        for (int j = 0; j < 8; j++) {
            atomicAdd(&acc[cg * 8 + j], ss[cg * 8 + j]);
            atomicAdd(&acc[CO + cg * 8 + j], sq2[cg * 8 + j]);
        }
    }
}

template <int CO>
__global__ void stats_fin(const float* __restrict__ acc, const float* __restrict__ gamma,
                          const float* __restrict__ beta, float* __restrict__ st) {
    int c = threadIdx.x;
    if (c < CO) {
        const float inv = 1.0f / (8192.0f * 81.0f);
        float m = acc[c] * inv;
        float var = acc[CO + c] * inv - m * m;
        float istd = rsqrtf(var + 1e-5f);
        float sc = istd * gamma[c];
        st[c] = sc;
        st[CO + c] = beta[c] - m * sc;
    }
}

// ---------------- in-place BN+relu apply on bf16 [rows][CO] ----------------
template <int CO>
__global__ __launch_bounds__(256) void bn_apply(bf16* __restrict__ x,
                                                const float* __restrict__ st) {
    const int tid = blockIdx.x * 256 + threadIdx.x;
    const int stride = gridDim.x * 256;
    const int ci0 = (tid * 8) % CO;
    float sc[8], sh[8];
#pragma unroll
    for (int j = 0; j < 8; j++) { sc[j] = st[ci0 + j]; sh[j] = st[CO + ci0 + j]; }
    const int TOT8 = NIMG * 81 * CO / 8;
    uint4* xp = (uint4*)x;
    for (int i = tid; i < TOT8; i += stride) {
        uint4 u = xp[i];
        float v[8] = {bflo(u.x), bfhi(u.x), bflo(u.y), bfhi(u.y),
                      bflo(u.z), bfhi(u.z), bflo(u.w), bfhi(u.w)};
        unsigned short us[8];
#pragma unroll
        for (int j = 0; j < 8; j++)
            us[j] = f2bf(fmaxf(fmaf(v[j], sc[j], sh[j]), 0.f));
        uint4 o;
        o.x = us[0] | ((unsigned)us[1] << 16);
        o.y = us[2] | ((unsigned)us[3] << 16);
        o.z = us[4] | ((unsigned)us[5] << 16);
        o.w = us[6] | ((unsigned)us[7] << 16);
        xp[i] = o;
    }
}

__global__ void enc_reduce(const float* __restrict__ part, const float* __restrict__ encb,
                           float* __restrict__ xE) {
    int i = blockIdx.x * 256 + threadIdx.x;
    const int NP = NIMG * 128;
    if (i < NP)
        xE[i] = part[i] + part[NP + i] + part[2 * NP + i] + part[3 * NP + i] + encb[i & 127];
}

// xT[b][f][n] = xE[b*128+n][f]
__global__ __launch_bounds__(256) void transpose_xe(const float* __restrict__ xE,
                                                    float* __restrict__ xT) {
    int b = blockIdx.x, t = threadIdx.x;
    const float* src = xE + (size_t)b * 16384;
    float* dst = xT + (size_t)b * 16384;
    for (int i = t; i < 16384; i += 256) {
        int n = i & 127, f = i >> 7;
        dst[i] = src[n * 128 + f];
    }
}

// Y[b] = A[b] (128x128) @ S[b] (128x128)
__global__ __launch_bounds__(256) void mm_xs(const float* __restrict__ A,
        const float* __restrict__ S, float* __restrict__ Y) {
    __shared__ __align__(16) float Sc[32 * 132];
    __shared__ float Acm[32 * 33];
    int b = blockIdx.y, f0 = blockIdx.x * 32;
    int t = threadIdx.x;
    int fl = t & 31, mg = t >> 5;
    const float* Ab = A + (size_t)b * 16384;
    const float* Sb = S + (size_t)b * 16384;
    float acc[16];
#pragma unroll
    for (int j = 0; j < 16; j++) acc[j] = 0.f;
    for (int nc = 0; nc < 128; nc += 32) {
#pragma unroll
        for (int r = 0; r < 4; r++) {
            int i4 = r * 256 + t;
            int nn = i4 >> 5, m4 = (i4 & 31) * 4;
            *(float4*)&Sc[nn * 132 + m4] = *(const float4*)&Sb[(size_t)(nc + nn) * 128 + m4];
        }
#pragma unroll
        for (int r = 0; r < 4; r++) {
            int i = r * 256 + t;
            int ff = i >> 5, nn = i & 31;
            Acm[ff * 33 + nn] = Ab[(size_t)(f0 + ff) * 128 + nc + nn];
        }
        __syncthreads();
#pragma unroll 4
        for (int nn = 0; nn < 32; nn++) {
            float a = Acm[fl * 33 + nn];
#pragma unroll
            for (int j = 0; j < 4; j++) {
                float4 s4 = *(const float4*)&Sc[nn * 132 + mg * 16 + j * 4];
                acc[j*4+0] = fmaf(a, s4.x, acc[j*4+0]);
                acc[j*4+1] = fmaf(a, s4.y, acc[j*4+1]);
                acc[j*4+2] = fmaf(a, s4.z, acc[j*4+2]);
                acc[j*4+3] = fmaf(a, s4.w, acc[j*4+3]);
            }
        }
        __syncthreads();
    }
    float* yb = Y + (size_t)b * 16384 + (size_t)(f0 + fl) * 128 + mg * 16;
#pragma unroll
    for (int j = 0; j < 4; j++)
        *(float4*)&yb[j * 4] = make_float4(acc[j*4], acc[j*4+1], acc[j*4+2], acc[j*4+3]);
}

// Out[b][g][n] = relu( sum_f W0[g,f]Z0 + W1 Z1 + W2 Z2 + bias[g] )
__global__ __launch_bounds__(256) void gf_combine(const float* __restrict__ Z0,
        const float* __restrict__ Z1, const float* __restrict__ Z2,
        const float* __restrict__ W, const float* __restrict__ bias,
        float* __restrict__ out) {
    __shared__ __align__(16) float Zc[32 * 132];
    __shared__ float Wc[32 * 33];
    int b = blockIdx.y, g0 = blockIdx.x * 32;
    int t = threadIdx.x;
    int gl = t & 31, mg = t >> 5;
    float acc[16];
    float bb = bias[g0 + gl];
#pragma unroll
    for (int j = 0; j < 16; j++) acc[j] = bb;
    const float* Zs[3] = {Z0 + (size_t)b * 16384, Z1 + (size_t)b * 16384, Z2 + (size_t)b * 16384};
    for (int j3 = 0; j3 < 3; j3++) {
        const float* Zb = Zs[j3];
        const float* Wj = W + j3 * 16384;
        for (int fc = 0; fc < 128; fc += 32) {
#pragma unroll
            for (int r = 0; r < 4; r++) {
                int i4 = r * 256 + t;
                int ff = i4 >> 5, m4 = (i4 & 31) * 4;
                *(float4*)&Zc[ff * 132 + m4] = *(const float4*)&Zb[(size_t)(fc + ff) * 128 + m4];
            }
#pragma unroll
            for (int r = 0; r < 4; r++) {
                int i = r * 256 + t;
                int gg = i >> 5, ff = i & 31;
                Wc[gg * 33 + ff] = Wj[(size_t)(g0 + gg) * 128 + fc + ff];
            }
            __syncthreads();
#pragma unroll 4
            for (int ff = 0; ff < 32; ff++) {
                float w = Wc[gl * 33 + ff];
#pragma unroll
                for (int j = 0; j < 4; j++) {
                    float4 z4 = *(const float4*)&Zc[ff * 132 + mg * 16 + j * 4];
                    acc[j*4+0] = fmaf(w, z4.x, acc[j*4+0]);
                    acc[j*4+1] = fmaf(w, z4.y, acc[j*4+1]);
                    acc[j*4+2] = fmaf(w, z4.z, acc[j*4+2]);
                    acc[j*4+3] = fmaf(w, z4.w, acc[j*4+3]);
                }
            }
            __syncthreads();
        }
    }
    float* ob = out + (size_t)b * 16384 + (size_t)(g0 + gl) * 128 + mg * 16;
#pragma unroll
    for (int j = 0; j < 4; j++)
        *(float4*)&ob[j * 4] = make_float4(fmaxf(acc[j*4], 0.f), fmaxf(acc[j*4+1], 0.f),
                                           fmaxf(acc[j*4+2], 0.f), fmaxf(acc[j*4+3], 0.f));
}

// logits[b,n,a] = sum_g X[b][g][n] * aw[a][g] + ab[a]
__global__ __launch_bounds__(128) void act_kernel(const float* __restrict__ X,
        const float* __restrict__ aw, const float* __restrict__ ab,
        float* __restrict__ out) {
    int b = blockIdx.x, n = threadIdx.x;
    float acc[5];
#pragma unroll
    for (int a = 0; a < 5; a++) acc[a] = ab[a];
    const float* xb = X + (size_t)b * 16384 + n;
#pragma unroll 4
    for (int g = 0; g < 128; g++) {
        float v = xb[(size_t)g * 128];
#pragma unroll
        for (int a = 0; a < 5; a++) acc[a] = fmaf(v, aw[a * 128 + g], acc[a]);
    }
    float* ob = out + ((size_t)b * 128 + n) * 5;
#pragma unroll
    for (int a = 0; a < 5; a++) ob[a] = acc[a];
}

// ---------------------------------------------------------------------------
extern "C" void kernel_launch(void* const* d_in, const int* in_sizes, int n_in,
                              void* d_out, int out_size, void* d_ws, size_t ws_size,
                              hipStream_t stream) {
    const float* states = (const float*)d_in[0];
    const float* gso    = (const float*)d_in[1];
    const float* c1w  = (const float*)d_in[2];
    const float* c1b  = (const float*)d_in[3];
    const float* c1g  = (const float*)d_in[4];
    const float* c1be = (const float*)d_in[5];
    const float* c2w  = (const float*)d_in[6];
    const float* c2b  = (const float*)d_in[7];
    const float* c2g  = (const float*)d_in[8];
    const float* c2be = (const float*)d_in[9];
    const float* c3w  = (const float*)d_in[10];
    const float* c3b  = (const float*)d_in[11];
    const float* c3g  = (const float*)d_in[12];
    const float* c3be = (const float*)d_in[13];
    const float* encw = (const float*)d_in[14];
    const float* encb = (const float*)d_in[15];
    const float* g1w  = (const float*)d_in[16];
    const float* g1b  = (const float*)d_in[17];
    const float* g2w  = (const float*)d_in[18];
    const float* g2b  = (const float*)d_in[19];
    const float* aw   = (const float*)d_in[20];
    const float* ab   = (const float*)d_in[21];
    float* out = (float*)d_out;
    char* ws = (char*)d_ws;

    size_t o = 0;
    auto take = [&](size_t bytes) { size_t r = o; o += (bytes + 255) & ~(size_t)255; return r; };
    const size_t o_x3  = take((size_t)NIMG * 81 * 128 * 2);   // 169,869,312
    const size_t o_x2  = take((size_t)NIMG * 81 * 64 * 2);    //  84,934,656
    const size_t o_w1t = take(27 * 32 * 4);
    const size_t o_w2m = take(64 * 288 * 2);
    const size_t o_w3m = take(128 * 576 * 2);
    const size_t o_acc = take(448 * 4);
    const size_t o_st1 = take(2 * 32 * 4);
    const size_t o_st2 = take(2 * 64 * 4);
    const size_t o_st3 = take(2 * 128 * 4);
    if (ws_size < o) {
        fill_sentinel<<<(out_size + 255) / 256, 256, 0, stream>>>(out, out_size);
        return;
    }

    const size_t o_x1 = o_x3;                       // x1 at head of x3 region
    const size_t o_ewb  = o_x2;                     // 2,654,208 (aliases dead x2)
    const size_t o_part = o_x2 + 2654208;           // 16,777,216 (4 k-split partials)
    const size_t o_xE   = o_part + 16777216;
    const size_t o_xT   = o_xE + 4194304;
    const size_t o_y1   = o_xT + 4194304;
    const size_t o_y2   = o_y1 + 4194304;
    const size_t o_G1   = o_y2 + 4194304;
    const size_t o_G2   = o_G1 + 4194304;           // ends ~44.6MB < 85MB region

    bf16* x1 = (bf16*)(ws + o_x1);
    bf16* x2 = (bf16*)(ws + o_x2);
    bf16* x3 = (bf16*)(ws + o_x3);
    float* w1t = (float*)(ws + o_w1t);
    bf16* w2m = (bf16*)(ws + o_w2m);
    bf16* w3m = (bf16*)(ws + o_w3m);
    float* acc1 = (float*)(ws + o_acc);
    float* acc2 = acc1 + 64;
    float* acc3 = acc1 + 192;
    float* st1 = (float*)(ws + o_st1);
    float* st2 = (float*)(ws + o_st2);
    float* st3 = (float*)(ws + o_st3);
    bf16* ewb = (bf16*)(ws + o_ewb);
    float* partp = (float*)(ws + o_part);
    float* xE = (float*)(ws + o_xE);
    float* xT = (float*)(ws + o_xT);
    float* y1 = (float*)(ws + o_y1);
    float* y2 = (float*)(ws + o_y2);
    float* xG1 = (float*)(ws + o_G1);
    float* xG2 = (float*)(ws + o_G2);

    hipMemsetAsync(ws + o_acc, 0, 448 * 4, stream);
    prep_w<<<128, 256, 0, stream>>>(c1w, c2w, c3w, w1t, w2m, w3m);

    conv1_kernel<<<2048, 128, 0, stream>>>(states, w1t, c1b, x1);
    stats_pass<32><<<256, 256, 0, stream>>>(x1, acc1);
    stats_fin<32><<<1, 32, 0, stream>>>(acc1, c1g, c1be, st1);
    bn_apply<32><<<2048, 256, 0, stream>>>(x1, st1);

    conv_mfma<32, 64, 4, 1><<<5184, 256, 0, stream>>>(x1, w2m, c2b, x2);
    stats_pass<64><<<256, 256, 0, stream>>>(x2, acc2);
    stats_fin<64><<<1, 64, 0, stream>>>(acc2, c2g, c2be, st2);
    bn_apply<64><<<2048, 256, 0, stream>>>(x2, st2);

    conv_mfma<64, 128, 4, 2><<<10368, 256, 0, stream>>>(x2, w3m, c3b, x3);
    stats_pass<128><<<256, 256, 0, stream>>>(x3, acc3);
    stats_fin<128><<<1, 128, 0, stream>>>(acc3, c3g, c3be, st3);
    bn_apply<128><<<2048, 256, 0, stream>>>(x3, st3);

    prep_enc<<<2048, 256, 0, stream>>>(encw, ewb);
    enc_mfma<<<512, 256, 0, stream>>>(x3, ewb, partp);
    enc_reduce<<<4096, 256, 0, stream>>>(partp, encb, xE);
    transpose_xe<<<64, 256, 0, stream>>>(xE, xT);

    mm_xs<<<dim3(4, 64), 256, 0, stream>>>(xT, gso, y1);
    mm_xs<<<dim3(4, 64), 256, 0, stream>>>(y1, gso, y2);
    gf_combine<<<dim3(4, 64), 256, 0, stream>>>(xT, y1, y2, g1w, g1b, xG1);

    mm_xs<<<dim3(4, 64), 256, 0, stream>>>(xG1, gso, y1);
    mm_xs<<<dim3(4, 64), 256, 0, stream>>>(y1, gso, y2);
    gf_combine<<<dim3(4, 64), 256, 0, stream>>>(xG1, y1, y2, g2w, g2b, xG2);

    act_kernel<<<64, 128, 0, stream>>>(xG2, aw, ab, out);
}

// Round 6
// 976.310 us; speedup vs baseline: 2.9253x; 1.3574x over previous
//
#include <hip/hip_runtime.h>
#include <hip/hip_bf16.h>
#include <stdint.h>

// ---------------------------------------------------------------------------
// Network_60163901882451 — round 6: conv2/conv3 as LDS-staged implicit GEMM.
// Block = 256 imgs x 64 oc x 1 pixel; weights (37-74KB) staged to LDS once,
// B-frags via ds_read_b128; M=64/wave (4 A-sets) -> 16 MFMAs per 4 loads.
// A direct global 16B loads, one-step prefetch. Encoder: register-prefetched
// GEMM, XCD keeps its ewb slice L2-resident. (R5 lesson: latency, not BW.)
// ---------------------------------------------------------------------------

#define NIMG 8192
#define NPIX 81
#define FLAT 10368

typedef __hip_bfloat16 bf16;
typedef short bf16x8 __attribute__((ext_vector_type(8)));
typedef float f32x4 __attribute__((ext_vector_type(4)));

__device__ __forceinline__ float bflo(unsigned u) { return __uint_as_float(u << 16); }
__device__ __forceinline__ float bfhi(unsigned u) { return __uint_as_float(u & 0xffff0000u); }
__device__ __forceinline__ unsigned short f2bf(float f) {
    unsigned u = __float_as_uint(f);
    return (unsigned short)((u + 0x7fff + ((u >> 16) & 1)) >> 16);
}

__global__ void fill_sentinel(float* __restrict__ out, int n) {
    int i = blockIdx.x * 256 + threadIdx.x;
    if (i < n) out[i] = 1.0e9f;   // ws_size-too-small signature
}

// ---------------- weight preps ---------------------------------------------
__global__ void prep_w(const float* __restrict__ c1w, const float* __restrict__ c2w,
                       const float* __restrict__ c3w,
                       float* __restrict__ w1t, bf16* __restrict__ w2m,
                       bf16* __restrict__ w3m) {
    int i0 = blockIdx.x * blockDim.x + threadIdx.x;
    int stride = gridDim.x * blockDim.x;
    for (int i = i0; i < 27 * 32; i += stride) w1t[i] = c1w[(i & 31) * 27 + (i >> 5)];
    for (int i = i0; i < 64 * 288; i += stride) {
        int oc = i / 288, r = i - oc * 288, t = r >> 5, ci = r & 31;
        w2m[i] = __float2bfloat16(c2w[oc * 288 + ci * 9 + t]);
    }
    for (int i = i0; i < 128 * 576; i += stride) {
        int oc = i / 576, r = i - oc * 576, t = r >> 6, ci = r & 63;
        w3m[i] = __float2bfloat16(c3w[oc * 576 + ci * 9 + t]);
    }
}

// ewb[e][px*128+ci] = encw[e][ci*81+px]
__global__ void prep_enc(const float* __restrict__ encw, bf16* __restrict__ ewb) {
    int i0 = blockIdx.x * blockDim.x + threadIdx.x;
    int stride = gridDim.x * blockDim.x;
    for (int i = i0; i < 128 * FLAT; i += stride) {
        int e = i / FLAT, r = i - e * FLAT;
        int px = r >> 7, ci = r & 127;
        ewb[i] = __float2bfloat16(encw[(size_t)e * FLAT + ci * 81 + px]);
    }
}

// ---------------- conv1 (direct fp32; tiny) --------------------------------
__device__ __forceinline__ void load_row(const float* __restrict__ p, float* r) {
    float4 a = *(const float4*)p;
    float4 b = *(const float4*)(p + 4);
    float4 c = *(const float4*)(p + 8);
    r[0]=a.x; r[1]=a.y; r[2]=a.z;  r[3]=a.w;
    r[4]=b.x; r[5]=b.y; r[6]=b.z;  r[7]=b.w;
    r[8]=c.x; r[9]=c.y; r[10]=c.z; r[11]=c.w;
}

__device__ __forceinline__ void conv_body(const float* __restrict__ inp,
                                          const float* __restrict__ wv, float* acc) {
    float rb[3][12];
    load_row(inp, rb[0]);
    load_row(inp + 12, rb[1]);
#pragma unroll
    for (int oy = 0; oy < 9; oy++) {
        load_row(inp + (oy + 2) * 12, rb[(oy + 2) % 3]);
#pragma unroll
        for (int ky = 0; ky < 3; ky++) {
            const float* r = rb[(oy + ky) % 3];
#pragma unroll
            for (int ox = 0; ox < 9; ox++) {
                float s = acc[oy * 9 + ox];
                s = fmaf(r[ox + 0], wv[ky * 3 + 0], s);
                s = fmaf(r[ox + 1], wv[ky * 3 + 1], s);
                s = fmaf(r[ox + 2], wv[ky * 3 + 2], s);
                acc[oy * 9 + ox] = s;
            }
        }
    }
}

__global__ __launch_bounds__(128) void conv1_kernel(const float* __restrict__ xin,
        const float* __restrict__ wt, const float* __restrict__ bias,
        bf16* __restrict__ xout) {
    __shared__ __align__(16) float lds[4 * 3 * 132];
    int t = threadIdx.x;
    int img0 = blockIdx.x * 4;
    for (int i = t; i < 4 * 3 * 132; i += 128) lds[i] = 0.f;
    __syncthreads();
    const float* src = xin + (size_t)img0 * 243;
    for (int i = t; i < 4 * 243; i += 128) {
        int il = i / 243, rem = i - il * 243;
        int ci = rem / 81, px = rem - ci * 81;
        lds[(il * 3 + ci) * 132 + (px / 9 + 1) * 12 + (px % 9) + 1] = src[i];
    }
    __syncthreads();
    int oc = t & 31, il = t >> 5;
    const float* base = lds + il * 3 * 132;
    float acc[81];
    float bb = bias[oc];
#pragma unroll
    for (int i = 0; i < 81; i++) acc[i] = bb;
#pragma unroll
    for (int ci = 0; ci < 3; ci++) {
        float wv[9];
#pragma unroll
        for (int k = 0; k < 9; k++) wv[k] = wt[(ci * 9 + k) * 32 + oc];
        conv_body(base + ci * 132, wv, acc);
    }
    bf16* dst = xout + (size_t)(img0 + il) * 81 * 32 + oc;
#pragma unroll
    for (int p = 0; p < 81; p++) dst[p * 32] = __float2bfloat16(acc[p]);
}

// ---------------- LDS-staged MFMA conv -------------------------------------
// xin: post-BN bf16 [img][81][CI]; wm: bf16 [oc][9tap][CI]; out pre-BN bf16.
// Block: 256 imgs x 64 oc x 1 pixel. Grid = 8 xcd * (4 igl * 81 p * OCS).
template <int CI, int COT, int OCS>
__global__ __launch_bounds__(256) void conv_tile(const bf16* __restrict__ xin,
        const bf16* __restrict__ wm, const float* __restrict__ bias,
        bf16* __restrict__ xout) {
    constexpr int NCH = CI / 32;
    constexpr int ROW = 9 * CI;
    constexpr int PADROW = (CI == 64) ? 584 : 296;  // word-stride spreads banks
    constexpr int STEPS = 9 * NCH;
    __shared__ bf16 Bs[64 * PADROW];

    const int lin = blockIdx.x;
    const int xcd = lin & 7;
    const int slot = lin >> 3;
    constexpr int PSL = 81 * OCS;
    const int igl = slot / PSL;
    const int rem = slot - igl * PSL;
    const int p = rem / OCS;
    const int ob = rem - p * OCS;
    const int ig = xcd * 4 + igl;
    const int oc0 = ob * 64;
    const int py = p / 9, pxx = p - py * 9;
    const int tid = threadIdx.x;

    // stage weight slice [oc0, oc0+64) x ROW into LDS (padded rows)
    constexpr int CH16 = ROW / 8;
    for (int i = tid; i < 64 * CH16; i += 256) {
        int oc = i / CH16, j = i - oc * CH16;
        *(bf16x8*)(&Bs[oc * PADROW + j * 8]) =
            *(const bf16x8*)(wm + (size_t)(oc0 + oc) * ROW + j * 8);
    }

    int qt[9]; bool vt[9];
#pragma unroll
    for (int t = 0; t < 9; t++) {
        int iy = py + t / 3 - 1, ix = pxx + (t % 3) - 1;
        vt[t] = ((unsigned)iy < 9u) && ((unsigned)ix < 9u);
        qt[t] = vt[t] ? iy * 9 + ix : p;   // clamped safe address
    }

    const int lane = tid & 63, wv = tid >> 6;
    const int m = lane & 15, quad = lane >> 4;
    const long img0 = (long)ig * 256 + wv * 64;

    f32x4 acc[4][4];
#pragma unroll
    for (int nf = 0; nf < 4; nf++) {
        float bb = bias[oc0 + nf * 16 + m];
#pragma unroll
        for (int ms = 0; ms < 4; ms++) {
            acc[ms][nf][0] = bb; acc[ms][nf][1] = bb;
            acc[ms][nf][2] = bb; acc[ms][nf][3] = bb;
        }
    }
    const bf16* ab[4];
#pragma unroll
    for (int ms = 0; ms < 4; ms++)
        ab[ms] = xin + (img0 + ms * 16 + m) * (81 * CI) + quad * 8;
    const bf16* bs = &Bs[m * PADROW + quad * 8];

    __syncthreads();   // LDS fill complete; no further barriers

    const bf16x8 zf = {0, 0, 0, 0, 0, 0, 0, 0};
    bf16x8 Ac[4];
#pragma unroll
    for (int ms = 0; ms < 4; ms++) Ac[ms] = *(const bf16x8*)(ab[ms] + qt[0] * CI);

#pragma unroll
    for (int s = 0; s < STEPS; s++) {
        const int t = s / NCH, ch = s - t * NCH;
        bf16x8 An[4];
        if (s + 1 < STEPS) {
            const int t2 = (s + 1) / NCH, ch2 = (s + 1) - t2 * NCH;
#pragma unroll
            for (int ms = 0; ms < 4; ms++)
                An[ms] = *(const bf16x8*)(ab[ms] + qt[t2] * CI + ch2 * 32);
        }
        bf16x8 av[4];
#pragma unroll
        for (int ms = 0; ms < 4; ms++) av[ms] = vt[t] ? Ac[ms] : zf;
#pragma unroll
        for (int nf = 0; nf < 4; nf++) {
            bf16x8 b = *(const bf16x8*)(bs + nf * 16 * PADROW + t * CI + ch * 32);
#pragma unroll
            for (int ms = 0; ms < 4; ms++)
                acc[ms][nf] = __builtin_amdgcn_mfma_f32_16x16x32_bf16(av[ms], b, acc[ms][nf], 0, 0, 0);
        }
#pragma unroll
        for (int ms = 0; ms < 4; ms++) Ac[ms] = An[ms];
    }

    // D: col = lane&15 (oc), row = quad*4 + reg (img)
    bf16* orow = xout + (img0 + quad * 4) * (81 * COT) + (size_t)p * COT + oc0 + m;
#pragma unroll
    for (int ms = 0; ms < 4; ms++)
#pragma unroll
        for (int nf = 0; nf < 4; nf++)
#pragma unroll
            for (int r = 0; r < 4; r++)
                orow[(size_t)(ms * 16 + r) * (81 * COT) + nf * 16] =
                    __float2bfloat16(acc[ms][nf][r]);
}

// ---------------- encoder: M=8192, N=128, K=10368 --------------------------
// Grid 256: xcd = lin&7 owns igl(4) x {ks(4) x nh(2)}; all of ewb L2-hot/XCD.
// Per block: 256 imgs x 64 oc x K-quarter; M=64/wave; A+B prefetch 1 step.
__global__ __launch_bounds__(256) void enc_mfma(const bf16* __restrict__ x3,
        const bf16* __restrict__ ewb, float* __restrict__ part) {
    const int lin = blockIdx.x;
    const int xcd = lin & 7;
    const int slot = lin >> 3;           // 0..31
    const int igl = slot >> 3;
    const int combo = slot & 7;
    const int ks = combo >> 1, nh = combo & 1;
    const int ig = xcd * 4 + igl;
    const int lane = threadIdx.x & 63, wv = threadIdx.x >> 6;
    const int m = lane & 15, quad = lane >> 4;
    const long img0 = (long)ig * 256 + wv * 64;

    f32x4 acc[4][4];
#pragma unroll
    for (int ms = 0; ms < 4; ms++)
#pragma unroll
        for (int nf = 0; nf < 4; nf++) {
            acc[ms][nf][0]=0.f; acc[ms][nf][1]=0.f; acc[ms][nf][2]=0.f; acc[ms][nf][3]=0.f;
        }
    const bf16* ab[4];
    const bf16* bb[4];
#pragma unroll
    for (int ms = 0; ms < 4; ms++)
        ab[ms] = x3 + (img0 + ms * 16 + m) * FLAT + ks * 2592 + quad * 8;
#pragma unroll
    for (int nf = 0; nf < 4; nf++)
        bb[nf] = ewb + (size_t)(nh * 64 + nf * 16 + m) * FLAT + ks * 2592 + quad * 8;

    bf16x8 Ac[4], Bc[4];
#pragma unroll
    for (int ms = 0; ms < 4; ms++) Ac[ms] = *(const bf16x8*)(ab[ms]);
#pragma unroll
    for (int nf = 0; nf < 4; nf++) Bc[nf] = *(const bf16x8*)(bb[nf]);

#pragma unroll 3
    for (int c = 0; c < 81; c++) {
        bf16x8 An[4], Bn[4];
        if (c + 1 < 81) {
#pragma unroll
            for (int ms = 0; ms < 4; ms++) An[ms] = *(const bf16x8*)(ab[ms] + (c + 1) * 32);
#pragma unroll
            for (int nf = 0; nf < 4; nf++) Bn[nf] = *(const bf16x8*)(bb[nf] + (c + 1) * 32);
        }
#pragma unroll
        for (int nf = 0; nf < 4; nf++)
#pragma unroll
            for (int ms = 0; ms < 4; ms++)
                acc[ms][nf] = __builtin_amdgcn_mfma_f32_16x16x32_bf16(Ac[ms], Bc[nf], acc[ms][nf], 0, 0, 0);
#pragma unroll
        for (int ms = 0; ms < 4; ms++) Ac[ms] = An[ms];
#pragma unroll
        for (int nf = 0; nf < 4; nf++) Bc[nf] = Bn[nf];
    }

    float* pp = part + (size_t)ks * (NIMG * 128) + (img0 + quad * 4) * 128 + nh * 64 + m;
#pragma unroll
    for (int ms = 0; ms < 4; ms++)
#pragma unroll
        for (int nf = 0; nf < 4; nf++)
#pragma unroll
            for (int r = 0; r < 4; r++)
                pp[(ms * 16 + r) * 128 + nf * 16] = acc[ms][nf][r];
}

// ---------------- per-channel sum / sumsq over [663552][CO] bf16 -----------
template <int CO>
__global__ __launch_bounds__(256) void stats_pass(const bf16* __restrict__ x,
                                                  float* __restrict__ acc) {
    constexpr int CH8 = CO / 8;
    constexpr int NG = 256 / CH8;
    __shared__ float ss[2048], sq2[2048];
    int t = threadIdx.x;
    int cg = t % CH8, grp = t / CH8;
    float s[8], q[8];
#pragma unroll
    for (int j = 0; j < 8; j++) { s[j] = 0.f; q[j] = 0.f; }
    const int ROWS = NIMG * 81;
    for (int row = blockIdx.x * NG + grp; row < ROWS; row += gridDim.x * NG) {
        uint4 u = *(const uint4*)(x + (size_t)row * CO + cg * 8);
        float vv[8] = {bflo(u.x), bfhi(u.x), bflo(u.y), bfhi(u.y),
                       bflo(u.z), bfhi(u.z), bflo(u.w), bfhi(u.w)};
#pragma unroll
        for (int j = 0; j < 8; j++) { s[j] += vv[j]; q[j] = fmaf(vv[j], vv[j], q[j]); }
    }
#pragma unroll
    for (int j = 0; j < 8; j++) {
        ss[grp * CO + cg * 8 + j] = s[j];
        sq2[grp * CO + cg * 8 + j] = q[j];
    }
    __syncthreads();
    for (int step = NG / 2; step > 0; step >>= 1) {
        if (grp < step) {
#pragma unroll
            for (int j = 0; j < 8; j++) {
                ss[grp * CO + cg * 8 + j] += ss[(grp + step) * CO + cg * 8 + j];
                sq2[grp * CO + cg * 8 + j] += sq2[(grp + step) * CO + cg * 8 + j];
            }
        }
        __syncthreads();
    }
    if (grp == 0) {
#pragma unroll
        for (int j = 0; j < 8; j++) {
            atomicAdd(&acc[cg * 8 + j], ss[cg * 8 + j]);
            atomicAdd(&acc[CO + cg * 8 + j], sq2[cg * 8 + j]);
        }
    }
}

template <int CO>
__global__ void stats_fin(const float* __restrict__ acc, const float* __restrict__ gamma,
                          const float* __restrict__ beta, float* __restrict__ st) {
    int c = threadIdx.x;
    if (c < CO) {
        const float inv = 1.0f / (8192.0f * 81.0f);
        float m = acc[c] * inv;
        float var = acc[CO + c] * inv - m * m;
        float istd = rsqrtf(var + 1e-5f);
        float sc = istd * gamma[c];
        st[c] = sc;
        st[CO + c] = beta[c] - m * sc;
    }
}

// ---------------- in-place BN+relu apply on bf16 [rows][CO] ----------------
template <int CO>
__global__ __launch_bounds__(256) void bn_apply(bf16* __restrict__ x,
                                                const float* __restrict__ st) {
    const int tid = blockIdx.x * 256 + threadIdx.x;
    const int stride = gridDim.x * 256;
    const int ci0 = (tid * 8) % CO;
    float sc[8], sh[8];
#pragma unroll
    for (int j = 0; j < 8; j++) { sc[j] = st[ci0 + j]; sh[j] = st[CO + ci0 + j]; }
    const int TOT8 = NIMG * 81 * CO / 8;
    uint4* xp = (uint4*)x;
    for (int i = tid; i < TOT8; i += stride) {
        uint4 u = xp[i];
        float v[8] = {bflo(u.x), bfhi(u.x), bflo(u.y), bfhi(u.y),
                      bflo(u.z), bfhi(u.z), bflo(u.w), bfhi(u.w)};
        unsigned short us[8];
#pragma unroll
        for (int j = 0; j < 8; j++)
            us[j] = f2bf(fmaxf(fmaf(v[j], sc[j], sh[j]), 0.f));
        uint4 o;
        o.x = us[0] | ((unsigned)us[1] << 16);
        o.y = us[2] | ((unsigned)us[3] << 16);
        o.z = us[4] | ((unsigned)us[5] << 16);
        o.w = us[6] | ((unsigned)us[7] << 16);
        xp[i] = o;
    }
}

__global__ void enc_reduce(const float* __restrict__ part, const float* __restrict__ encb,
                           float* __restrict__ xE) {
    int i = blockIdx.x * 256 + threadIdx.x;
    const int NP = NIMG * 128;
    if (i < NP)
        xE[i] = part[i] + part[NP + i] + part[2 * NP + i] + part[3 * NP + i] + encb[i & 127];
}

// xT[b][f][n] = xE[b*128+n][f]
__global__ __launch_bounds__(256) void transpose_xe(const float* __restrict__ xE,
                                                    float* __restrict__ xT) {
    int b = blockIdx.x, t = threadIdx.x;
    const float* src = xE + (size_t)b * 16384;
    float* dst = xT + (size_t)b * 16384;
    for (int i = t; i < 16384; i += 256) {
        int n = i & 127, f = i >> 7;
        dst[i] = src[n * 128 + f];
    }
}

// Y[b] = A[b] (128x128) @ S[b] (128x128)
__global__ __launch_bounds__(256) void mm_xs(const float* __restrict__ A,
        const float* __restrict__ S, float* __restrict__ Y) {
    __shared__ __align__(16) float Sc[32 * 132];
    __shared__ float Acm[32 * 33];
    int b = blockIdx.y, f0 = blockIdx.x * 32;
    int t = threadIdx.x;
    int fl = t & 31, mg = t >> 5;
    const float* Ab = A + (size_t)b * 16384;
    const float* Sb = S + (size_t)b * 16384;
    float acc[16];
#pragma unroll
    for (int j = 0; j < 16; j++) acc[j] = 0.f;
    for (int nc = 0; nc < 128; nc += 32) {
#pragma unroll
        for (int r = 0; r < 4; r++) {
            int i4 = r * 256 + t;
            int nn = i4 >> 5, m4 = (i4 & 31) * 4;
            *(float4*)&Sc[nn * 132 + m4] = *(const float4*)&Sb[(size_t)(nc + nn) * 128 + m4];
        }
#pragma unroll
        for (int r = 0; r < 4; r++) {
            int i = r * 256 + t;
            int ff = i >> 5, nn = i & 31;
            Acm[ff * 33 + nn] = Ab[(size_t)(f0 + ff) * 128 + nc + nn];
        }
        __syncthreads();
#pragma unroll 4
        for (int nn = 0; nn < 32; nn++) {
            float a = Acm[fl * 33 + nn];
#pragma unroll
            for (int j = 0; j < 4; j++) {
                float4 s4 = *(const float4*)&Sc[nn * 132 + mg * 16 + j * 4];
                acc[j*4+0] = fmaf(a, s4.x, acc[j*4+0]);
                acc[j*4+1] = fmaf(a, s4.y, acc[j*4+1]);
                acc[j*4+2] = fmaf(a, s4.z, acc[j*4+2]);
                acc[j*4+3] = fmaf(a, s4.w, acc[j*4+3]);
            }
        }
        __syncthreads();
    }
    float* yb = Y + (size_t)b * 16384 + (size_t)(f0 + fl) * 128 + mg * 16;
#pragma unroll
    for (int j = 0; j < 4; j++)
        *(float4*)&yb[j * 4] = make_float4(acc[j*4], acc[j*4+1], acc[j*4+2], acc[j*4+3]);
}

// Out[b][g][n] = relu( sum_f W0[g,f]Z0 + W1 Z1 + W2 Z2 + bias[g] )
__global__ __launch_bounds__(256) void gf_combine(const float* __restrict__ Z0,
        const float* __restrict__ Z1, const float* __restrict__ Z2,
        const float* __restrict__ W, const float* __restrict__ bias,
        float* __restrict__ out) {
    __shared__ __align__(16) float Zc[32 * 132];
    __shared__ float Wc[32 * 33];
    int b = blockIdx.y, g0 = blockIdx.x * 32;
    int t = threadIdx.x;
    int gl = t & 31, mg = t >> 5;
    float acc[16];
    float bb = bias[g0 + gl];
#pragma unroll
    for (int j = 0; j < 16; j++) acc[j] = bb;
    const float* Zs[3] = {Z0 + (size_t)b * 16384, Z1 + (size_t)b * 16384, Z2 + (size_t)b * 16384};
    for (int j3 = 0; j3 < 3; j3++) {
        const float* Zb = Zs[j3];
        const float* Wj = W + j3 * 16384;
        for (int fc = 0; fc < 128; fc += 32) {
#pragma unroll
            for (int r = 0; r < 4; r++) {
                int i4 = r * 256 + t;
                int ff = i4 >> 5, m4 = (i4 & 31) * 4;
                *(float4*)&Zc[ff * 132 + m4] = *(const float4*)&Zb[(size_t)(fc + ff) * 128 + m4];
            }
#pragma unroll
            for (int r = 0; r < 4; r++) {
                int i = r * 256 + t;
                int gg = i >> 5, ff = i & 31;
                Wc[gg * 33 + ff] = Wj[(size_t)(g0 + gg) * 128 + fc + ff];
            }
            __syncthreads();
#pragma unroll 4
            for (int ff = 0; ff < 32; ff++) {
                float w = Wc[gl * 33 + ff];
#pragma unroll
                for (int j = 0; j < 4; j++) {
                    float4 z4 = *(const float4*)&Zc[ff * 132 + mg * 16 + j * 4];
                    acc[j*4+0] = fmaf(w, z4.x, acc[j*4+0]);
                    acc[j*4+1] = fmaf(w, z4.y, acc[j*4+1]);
                    acc[j*4+2] = fmaf(w, z4.z, acc[j*4+2]);
                    acc[j*4+3] = fmaf(w, z4.w, acc[j*4+3]);
                }
            }
            __syncthreads();
        }
    }
    float* ob = out + (size_t)b * 16384 + (size_t)(g0 + gl) * 128 + mg * 16;
#pragma unroll
    for (int j = 0; j < 4; j++)
        *(float4*)&ob[j * 4] = make_float4(fmaxf(acc[j*4], 0.f), fmaxf(acc[j*4+1], 0.f),
                                           fmaxf(acc[j*4+2], 0.f), fmaxf(acc[j*4+3], 0.f));
}

// logits[b,n,a] = sum_g X[b][g][n] * aw[a][g] + ab[a]
__global__ __launch_bounds__(128) void act_kernel(const float* __restrict__ X,
        const float* __restrict__ aw, const float* __restrict__ ab,
        float* __restrict__ out) {
    int b = blockIdx.x, n = threadIdx.x;
    float acc[5];
#pragma unroll
    for (int a = 0; a < 5; a++) acc[a] = ab[a];
    const float* xb = X + (size_t)b * 16384 + n;
#pragma unroll 4
    for (int g = 0; g < 128; g++) {
        float v = xb[(size_t)g * 128];
#pragma unroll
        for (int a = 0; a < 5; a++) acc[a] = fmaf(v, aw[a * 128 + g], acc[a]);
    }
    float* ob = out + ((size_t)b * 128 + n) * 5;
#pragma unroll
    for (int a = 0; a < 5; a++) ob[a] = acc[a];
}

// ---------------------------------------------------------------------------
extern "C" void kernel_launch(void* const* d_in, const int* in_sizes, int n_in,
                              void* d_out, int out_size, void* d_ws, size_t ws_size,
                              hipStream_t stream) {
    const float* states = (const float*)d_in[0];
    const float* gso    = (const float*)d_in[1];
    const float* c1w  = (const float*)d_in[2];
    const float* c1b  = (const float*)d_in[3];
    const float* c1g  = (const float*)d_in[4];
    const float* c1be = (const float*)d_in[5];
    const float* c2w  = (const float*)d_in[6];
    const float* c2b  = (const float*)d_in[7];
    const float* c2g  = (const float*)d_in[8];
    const float* c2be = (const float*)d_in[9];
    const float* c3w  = (const float*)d_in[10];
    const float* c3b  = (const float*)d_in[11];
    const float* c3g  = (const float*)d_in[12];
    const float* c3be = (const float*)d_in[13];
    const float* encw = (const float*)d_in[14];
    const float* encb = (const float*)d_in[15];
    const float* g1w  = (const float*)d_in[16];
    const float* g1b  = (const float*)d_in[17];
    const float* g2w  = (const float*)d_in[18];
    const float* g2b  = (const float*)d_in[19];
    const float* aw   = (const float*)d_in[20];
    const float* ab   = (const float*)d_in[21];
    float* out = (float*)d_out;
    char* ws = (char*)d_ws;

    size_t o = 0;
    auto take = [&](size_t bytes) { size_t r = o; o += (bytes + 255) & ~(size_t)255; return r; };
    const size_t o_x3  = take((size_t)NIMG * 81 * 128 * 2);   // 169,869,312
    const size_t o_x2  = take((size_t)NIMG * 81 * 64 * 2);    //  84,934,656
    const size_t o_w1t = take(27 * 32 * 4);
    const size_t o_w2m = take(64 * 288 * 2);
    const size_t o_w3m = take(128 * 576 * 2);
    const size_t o_acc = take(448 * 4);
    const size_t o_st1 = take(2 * 32 * 4);
    const size_t o_st2 = take(2 * 64 * 4);
    const size_t o_st3 = take(2 * 128 * 4);
    if (ws_size < o) {
        fill_sentinel<<<(out_size + 255) / 256, 256, 0, stream>>>(out, out_size);
        return;
    }

    const size_t o_x1 = o_x3;                       // x1 at head of x3 region
    const size_t o_ewb  = o_x2;                     // 2,654,208 (aliases dead x2)
    const size_t o_part = o_x2 + 2654208;           // 16,777,216 (4 k-split partials)
    const size_t o_xE   = o_part + 16777216;
    const size_t o_xT   = o_xE + 4194304;
    const size_t o_y1   = o_xT + 4194304;
    const size_t o_y2   = o_y1 + 4194304;
    const size_t o_G1   = o_y2 + 4194304;
    const size_t o_G2   = o_G1 + 4194304;           // ends ~44.6MB < 85MB region

    bf16* x1 = (bf16*)(ws + o_x1);
    bf16* x2 = (bf16*)(ws + o_x2);
    bf16* x3 = (bf16*)(ws + o_x3);
    float* w1t = (float*)(ws + o_w1t);
    bf16* w2m = (bf16*)(ws + o_w2m);
    bf16* w3m = (bf16*)(ws + o_w3m);
    float* acc1 = (float*)(ws + o_acc);
    float* acc2 = acc1 + 64;
    float* acc3 = acc1 + 192;
    float* st1 = (float*)(ws + o_st1);
    float* st2 = (float*)(ws + o_st2);
    float* st3 = (float*)(ws + o_st3);
    bf16* ewb = (bf16*)(ws + o_ewb);
    float* partp = (float*)(ws + o_part);
    float* xE = (float*)(ws + o_xE);
    float* xT = (float*)(ws + o_xT);
    float* y1 = (float*)(ws + o_y1);
    float* y2 = (float*)(ws + o_y2);
    float* xG1 = (float*)(ws + o_G1);
    float* xG2 = (float*)(ws + o_G2);

    hipMemsetAsync(ws + o_acc, 0, 448 * 4, stream);
    prep_w<<<128, 256, 0, stream>>>(c1w, c2w, c3w, w1t, w2m, w3m);

    conv1_kernel<<<2048, 128, 0, stream>>>(states, w1t, c1b, x1);
    stats_pass<32><<<256, 256, 0, stream>>>(x1, acc1);
    stats_fin<32><<<1, 32, 0, stream>>>(acc1, c1g, c1be, st1);
    bn_apply<32><<<2048, 256, 0, stream>>>(x1, st1);

    conv_tile<32, 64, 1><<<2592, 256, 0, stream>>>(x1, w2m, c2b, x2);
    stats_pass<64><<<256, 256, 0, stream>>>(x2, acc2);
    stats_fin<64><<<1, 64, 0, stream>>>(acc2, c2g, c2be, st2);
    bn_apply<64><<<2048, 256, 0, stream>>>(x2, st2);

    conv_tile<64, 128, 2><<<5184, 256, 0, stream>>>(x2, w3m, c3b, x3);
    stats_pass<128><<<256, 256, 0, stream>>>(x3, acc3);
    stats_fin<128><<<1, 128, 0, stream>>>(acc3, c3g, c3be, st3);
    bn_apply<128><<<2048, 256, 0, stream>>>(x3, st3);

    prep_enc<<<2048, 256, 0, stream>>>(encw, ewb);
    enc_mfma<<<256, 256, 0, stream>>>(x3, ewb, partp);
    enc_reduce<<<4096, 256, 0, stream>>>(partp, encb, xE);
    transpose_xe<<<64, 256, 0, stream>>>(xE, xT);

    mm_xs<<<dim3(4, 64), 256, 0, stream>>>(xT, gso, y1);
    mm_xs<<<dim3(4, 64), 256, 0, stream>>>(y1, gso, y2);
    gf_combine<<<dim3(4, 64), 256, 0, stream>>>(xT, y1, y2, g1w, g1b, xG1);

    mm_xs<<<dim3(4, 64), 256, 0, stream>>>(xG1, gso, y1);
    mm_xs<<<dim3(4, 64), 256, 0, stream>>>(y1, gso, y2);
    gf_combine<<<dim3(4, 64), 256, 0, stream>>>(xG1, y1, y2, g2w, g2b, xG2);

    act_kernel<<<64, 128, 0, stream>>>(xG2, aw, ab, out);
}